// Round 3
// baseline (1233.749 us; speedup 1.0000x reference)
//
#include <hip/hip_runtime.h>
#include <hip/hip_cooperative_groups.h>
#include <math.h>

namespace cg = cooperative_groups;

// ---------------------------------------------------------------------------
// HybridBERT4RecGNN forward on MI355X (gfx950), round 14.
//
// R13 counters: seq_transformer 82us unchanged; every GNN dispatch < 82us yet
// the non-transformer wall is ~295us while modeled GNN GPU work is ~100-150us.
// -> the hole is dispatch-count-proportional: ~10 serialized kernel
// boundaries (launch + drain of 12K-block grids) + device-scope atomic
// rounds with 16 counters sharing each 64B line (per-line serialization at
// the memory-side atomic units).
// R14:
//  (a) ONE cooperative kernel (1024 blocks x 256, grid.sync between phases)
//      replaces memset + prep_all + cvt_hist + 3 scan kernels + build +
//      gather1 + gather_avg: 10 dispatches -> 2 total (gnn_all + transformer).
//  (b) atomic counters padded to 1 per 64B line (cstr=16; runtime fallback
//      to 4/1 if workspace is tight) for the histogram AND the CSR append.
//  (c) wp aliases cnt (thread-local read-then-overwrite in the scan phase) -
//      saves 8MB, keeps the padded layout within workspace.
//  Transformer byte-identical to R12/R13. Coop-launch failure falls back to
//  the R13 multi-kernel path.
// ---------------------------------------------------------------------------

typedef __attribute__((ext_vector_type(8))) short bf16x8;
typedef __attribute__((ext_vector_type(4))) float f32x4;

#define SD   64
#define SS   50
#define NBLK 2
#define PH   72    // LDS pitch in halves (144 B, 16B-aligned rows, 2-way banks max)
#define GRID 1024  // cooperative grid: 4 blocks/CU x 256 CUs

__device__ __forceinline__ short f2b(float f) {  // fp32 -> bf16 RNE (HW cvt)
  union { __bf16 h; short s; } u;
  u.h = (__bf16)f;
  return u.s;
}
__device__ __forceinline__ float b2f(short s) {
  union { unsigned u; float f; } v;
  v.u = ((unsigned)(unsigned short)s) << 16;
  return v.f;
}
__device__ __forceinline__ unsigned packb(float a, float b) {
  union { __bf16 h; unsigned short s; } ua, ub;
  ua.h = (__bf16)a; ub.h = (__bf16)b;
  return (unsigned)ua.s | ((unsigned)ub.s << 16);
}
__device__ __forceinline__ float2 wred_sum2(float a, float b) {
#pragma unroll
  for (int o = 32; o > 0; o >>= 1) {
    a += __shfl_xor(a, o, 64);
    b += __shfl_xor(b, o, 64);
  }
  return make_float2(a, b);
}
// gelu(x) = 0.5x(1+tanh(u)) = x * sigmoid(2u);  sigmoid via v_rcp_f32.
__device__ __forceinline__ float gelu_fast(float x) {
  float u = 0.7978845608028654f * x * (1.0f + 0.044715f * x * x);
  float e = __expf(-2.f * u);
  return x * __builtin_amdgcn_rcpf(1.0f + e);
}

__device__ __forceinline__ bf16x8 ldB(const short* __restrict__ Wb, int tile, int lane) {
  return *(const bf16x8*)(Wb + ((size_t)tile * 64 + lane) * 8);
}

// [own 16 rows x K=64] @ [64x64] -> D own rows. A from LDS bf16 pitch PH.
__device__ __forceinline__ void mm64(const short* A, const short* __restrict__ Wb,
                                     int arow, int quad, int lane, f32x4 o4[4]) {
  bf16x8 a0 = *(const bf16x8*)(A + arow * PH + quad * 8);
  bf16x8 a1 = *(const bf16x8*)(A + arow * PH + 32 + quad * 8);
#pragma unroll
  for (int nt = 0; nt < 4; ++nt) {
    f32x4 acc = {0.f, 0.f, 0.f, 0.f};
    acc = __builtin_amdgcn_mfma_f32_16x16x32_bf16(a0, ldB(Wb, 0 * 4 + nt, lane), acc, 0, 0, 0);
    acc = __builtin_amdgcn_mfma_f32_16x16x32_bf16(a1, ldB(Wb, 1 * 4 + nt, lane), acc, 0, 0, 0);
    o4[nt] = acc;
  }
}

// LN over 64 cols of D-layout values + residual from xh + optional bias.
__device__ __forceinline__ void ln_epilogue(f32x4 o4[4], short* xh,
                                            const float* __restrict__ g,
                                            const float* __restrict__ bta,
                                            const float* __restrict__ extrab,
                                            int mt, int quad, int c0) {
  float vals[4][4];
  float s1[4] = {0.f, 0.f, 0.f, 0.f}, s2[4] = {0.f, 0.f, 0.f, 0.f};
#pragma unroll
  for (int nt = 0; nt < 4; ++nt) {
    int c = nt * 16 + c0;
    float eb = extrab ? extrab[c] : 0.f;
#pragma unroll
    for (int r = 0; r < 4; ++r) {
      int row = mt * 16 + quad * 4 + r;
      float v = o4[nt][r] + b2f(xh[row * PH + c]) + eb;
      vals[nt][r] = v;
      s1[r] += v;
      s2[r] += v * v;
    }
  }
#pragma unroll
  for (int o = 1; o < 16; o <<= 1) {
#pragma unroll
    for (int r = 0; r < 4; ++r) {
      s1[r] += __shfl_xor(s1[r], o, 64);
      s2[r] += __shfl_xor(s2[r], o, 64);
    }
  }
  float mv[4], rv[4];
#pragma unroll
  for (int r = 0; r < 4; ++r) {
    float m = s1[r] * (1.f / 64);
    float var = fmaxf(s2[r] * (1.f / 64) - m * m, 0.f);
    mv[r] = m;
    rv[r] = rsqrtf(var + 1e-5f);
  }
#pragma unroll
  for (int nt = 0; nt < 4; ++nt) {
    int c = nt * 16 + c0;
    float gv = g[c], bv = bta[c];
#pragma unroll
    for (int r = 0; r < 4; ++r) {
      int row = mt * 16 + quad * 4 + r;
      xh[row * PH + c] = f2b((vals[nt][r] - mv[r]) * rv[r] * gv + bv);
    }
  }
}

// ---------------------------------------------------------------------------
// Weight prep body (shared by standalone kernel and cooperative phase 0)
// ---------------------------------------------------------------------------
__device__ __forceinline__ void prep_body(int tid,
    const float* __restrict__ pw, const float* __restrict__ wq,
    const float* __restrict__ wk, const float* __restrict__ wv,
    const float* __restrict__ wo, const float* __restrict__ w1,
    const float* __restrict__ w2,
    short* __restrict__ pwB, short* __restrict__ wqB,
    short* __restrict__ wkB, short* __restrict__ wvB,
    short* __restrict__ woB, short* __restrict__ w1B,
    short* __restrict__ w2B) {
  int lane = tid & 63;
  int tile = tid >> 6;
  const float* W; short* out; int K, N, base;
  if (tile < 8)        { W = pw; out = pwB; K = 64;  N = 64;  base = 0; }
  else if (tile < 24)  { W = wq; out = wqB; K = 64;  N = 64;  base = 8; }
  else if (tile < 40)  { W = wk; out = wkB; K = 64;  N = 64;  base = 24; }
  else if (tile < 56)  { W = wv; out = wvB; K = 64;  N = 64;  base = 40; }
  else if (tile < 72)  { W = wo; out = woB; K = 64;  N = 64;  base = 56; }
  else if (tile < 136) { W = w1; out = w1B; K = 64;  N = 256; base = 72; }
  else if (tile < 200) { W = w2; out = w2B; K = 256; N = 64;  base = 136; }
  else return;
  int lt = tile - base;
  int KT = K / 32, NT = N / 16;
  int nt = lt % NT; lt /= NT;
  int kt = lt % KT; lt /= KT;
  int m = lt;
  const float* Wm = W + (size_t)m * K * N;
  int kbase = kt * 32 + ((lane >> 4) * 8);
  int n = nt * 16 + (lane & 15);
  short v[8];
#pragma unroll
  for (int j = 0; j < 8; ++j) v[j] = f2b(Wm[(size_t)(kbase + j) * N + n]);
  *(bf16x8*)(out + ((size_t)(tile - base) * 64 + lane) * 8) = *(bf16x8*)v;
}

__global__ void prep_all(const float* __restrict__ pw, const float* __restrict__ wq,
                         const float* __restrict__ wk, const float* __restrict__ wv,
                         const float* __restrict__ wo, const float* __restrict__ w1,
                         const float* __restrict__ w2,
                         short* __restrict__ pwB, short* __restrict__ wqB,
                         short* __restrict__ wkB, short* __restrict__ wvB,
                         short* __restrict__ woB, short* __restrict__ w1B,
                         short* __restrict__ w2B) {
  prep_body(blockIdx.x * blockDim.x + threadIdx.x,
            pw, wq, wk, wv, wo, w1, w2, pwB, wqB, wkB, wvB, woB, w1B, w2B);
}

// ---------------------------------------------------------------------------
// Gather bodies (shared). lane = slot*8 + g: slot walks edges beg+slot+8k;
// lane g reads uint4 (8 bf16 dims): 8 rows in flight, coalesced 128B rows.
// ---------------------------------------------------------------------------
__device__ __forceinline__ void gather1_node(int n, int lane,
    const unsigned* __restrict__ xinh, const int* __restrict__ rp,
    const int2* __restrict__ ep, unsigned* __restrict__ xouth) {
  int slot = lane >> 3;
  int g = lane & 7;
  int beg = rp[n], end = rp[n + 1];
  float a[8] = {0.f, 0.f, 0.f, 0.f, 0.f, 0.f, 0.f, 0.f};
  for (int e = beg + slot; e < end; e += 8) {
    int2 ee = ep[e];
    float w = __int_as_float(ee.y);
    uint4 p = *(const uint4*)(xinh + (size_t)ee.x * 32 + g * 4);
    a[0] += b2f((short)(p.x & 0xFFFF)) * w;
    a[1] += b2f((short)(p.x >> 16)) * w;
    a[2] += b2f((short)(p.y & 0xFFFF)) * w;
    a[3] += b2f((short)(p.y >> 16)) * w;
    a[4] += b2f((short)(p.z & 0xFFFF)) * w;
    a[5] += b2f((short)(p.z >> 16)) * w;
    a[6] += b2f((short)(p.w & 0xFFFF)) * w;
    a[7] += b2f((short)(p.w >> 16)) * w;
  }
#pragma unroll
  for (int o = 8; o < 64; o <<= 1)
#pragma unroll
    for (int j = 0; j < 8; ++j) a[j] += __shfl_xor(a[j], o, 64);
  if (slot == 0) {
    uint4 o4;
    o4.x = packb(a[0], a[1]);
    o4.y = packb(a[2], a[3]);
    o4.z = packb(a[4], a[5]);
    o4.w = packb(a[6], a[7]);
    *(uint4*)(xouth + (size_t)n * 32 + g * 4) = o4;
  }
}

__device__ __forceinline__ void gatheravg_node(int n, int lane,
    const unsigned* __restrict__ x1h, const int* __restrict__ rp,
    const int2* __restrict__ ep, const float* __restrict__ gnn,
    unsigned* __restrict__ avgh) {
  int slot = lane >> 3;
  int g = lane & 7;
  int beg = rp[n], end = rp[n + 1];
  float a[8] = {0.f, 0.f, 0.f, 0.f, 0.f, 0.f, 0.f, 0.f};
  for (int e = beg + slot; e < end; e += 8) {
    int2 ee = ep[e];
    float w = __int_as_float(ee.y);
    uint4 p = *(const uint4*)(x1h + (size_t)ee.x * 32 + g * 4);
    a[0] += b2f((short)(p.x & 0xFFFF)) * w;
    a[1] += b2f((short)(p.x >> 16)) * w;
    a[2] += b2f((short)(p.y & 0xFFFF)) * w;
    a[3] += b2f((short)(p.y >> 16)) * w;
    a[4] += b2f((short)(p.z & 0xFFFF)) * w;
    a[5] += b2f((short)(p.z >> 16)) * w;
    a[6] += b2f((short)(p.w & 0xFFFF)) * w;
    a[7] += b2f((short)(p.w >> 16)) * w;
  }
#pragma unroll
  for (int o = 8; o < 64; o <<= 1)
#pragma unroll
    for (int j = 0; j < 8; ++j) a[j] += __shfl_xor(a[j], o, 64);
  if (slot == 0) {
    uint4 own = *(const uint4*)(x1h + (size_t)n * 32 + g * 4);
    float4 g0 = *(const float4*)(gnn + (size_t)n * 64 + g * 8);
    float4 g1 = *(const float4*)(gnn + (size_t)n * 64 + g * 8 + 4);
    float v0 = (g0.x + b2f((short)(own.x & 0xFFFF)) + a[0]) * (1.f / 3.f);
    float v1 = (g0.y + b2f((short)(own.x >> 16)) + a[1]) * (1.f / 3.f);
    float v2 = (g0.z + b2f((short)(own.y & 0xFFFF)) + a[2]) * (1.f / 3.f);
    float v3 = (g0.w + b2f((short)(own.y >> 16)) + a[3]) * (1.f / 3.f);
    float v4 = (g1.x + b2f((short)(own.z & 0xFFFF)) + a[4]) * (1.f / 3.f);
    float v5 = (g1.y + b2f((short)(own.z >> 16)) + a[5]) * (1.f / 3.f);
    float v6 = (g1.z + b2f((short)(own.w & 0xFFFF)) + a[6]) * (1.f / 3.f);
    float v7 = (g1.w + b2f((short)(own.w >> 16)) + a[7]) * (1.f / 3.f);
    uint4 o4;
    o4.x = packb(v0, v1);
    o4.y = packb(v2, v3);
    o4.z = packb(v4, v5);
    o4.w = packb(v6, v7);
    *(uint4*)(avgh + (size_t)n * 32 + g * 4) = o4;
  }
}

// ---------------------------------------------------------------------------
// Cooperative mega-kernel: all GNN phases in one dispatch.
// counters padded: logical counter i lives at cntp[i*cs] (cs = 16/4/1).
// cnt and wp SHARE cntp (scan phase does thread-local read-then-overwrite).
// ---------------------------------------------------------------------------
struct GP {
  const float* gnn;
  const int* seq;
  const int* esrc; const int* edst; const float* ew;
  const float *pw, *wq, *wk, *wv, *wo, *w1, *w2;
  short *pwB, *wqB, *wkB, *wvB, *woB, *w1B, *w2B;
  unsigned *gnnh, *g1xh, *avgh;
  int* cntp; unsigned char* flags; int* bsum; int* rp; int2* ep;
  int N, E, BS, NCH, cs, n32, nfw;
};

__global__ __launch_bounds__(256, 4) void gnn_all(GP p) {
  cg::grid_group gg = cg::this_grid();
  __shared__ int shm[132];
  const int t = threadIdx.x, bx = blockIdx.x;
  const int tid = bx * 256 + t;
  const int NT = gridDim.x * 256;
  const int cs = p.cs;

  // ---- P0: zero counters+flags, cvt gnn->bf16 pairs, prep weights
  {
    int tot = p.NCH * 1024 * cs;
    for (int i = tid; i < tot; i += NT) p.cntp[i] = 0;
    int* fw = (int*)p.flags;
    for (int i = tid; i < p.nfw; i += NT) fw[i] = 0;
    for (int i = tid; i < p.n32; i += NT) {
      float2 f = ((const float2*)p.gnn)[i];
      p.gnnh[i] = packb(f.x, f.y);
    }
    prep_body(tid, p.pw, p.wq, p.wk, p.wv, p.wo, p.w1, p.w2,
              p.pwB, p.wqB, p.wkB, p.wvB, p.woB, p.w1B, p.w2B);
  }
  gg.sync();
  // ---- P1: dst histogram (padded atomics) + flag seq-referenced nodes
  for (int e = tid; e < p.E; e += NT) atomicAdd(&p.cntp[p.edst[e] * cs], 1);
  for (int i = tid; i < p.BS; i += NT) p.flags[p.seq[i]] = 1;
  gg.sync();
  // ---- P2a: per-chunk sums (first NCH blocks)
  if (bx < p.NCH) {
    if (t == 0) shm[0] = 0;
    __syncthreads();
    int base = bx * 1024 + t * 4;
    int s = p.cntp[base * cs] + p.cntp[(base + 1) * cs] +
            p.cntp[(base + 2) * cs] + p.cntp[(base + 3) * cs];
#pragma unroll
    for (int o = 32; o > 0; o >>= 1) s += __shfl_xor(s, o, 64);
    if ((t & 63) == 0) atomicAdd(&shm[0], s);
    __syncthreads();
    if (t == 0) p.bsum[bx] = shm[0];
  }
  gg.sync();
  // ---- P2b: scan chunk sums (block 0)
  if (bx == 0) {
    if (t < p.NCH) shm[t] = p.bsum[t];
    __syncthreads();
    if (t == 0) {
      int a = 0;
      for (int i = 0; i < p.NCH; ++i) { int v = shm[i]; shm[i] = a; a += v; }
    }
    __syncthreads();
    if (t < p.NCH) p.bsum[t] = shm[t];
  }
  gg.sync();
  // ---- P2c: per-chunk exclusive scan -> rp; wp (= cntp) reset to starts
  if (bx < p.NCH) {
    int lane = t & 63, wv = t >> 6;
    int base = bx * 1024 + t * 4;
    int c0 = p.cntp[base * cs], c1 = p.cntp[(base + 1) * cs];
    int c2 = p.cntp[(base + 2) * cs], c3 = p.cntp[(base + 3) * cs];
    int s = c0 + c1 + c2 + c3;
    int x = s;
#pragma unroll
    for (int o = 1; o < 64; o <<= 1) {
      int y = __shfl_up(x, o, 64);
      if (lane >= o) x += y;
    }
    if (lane == 63) shm[128 + wv] = x;
    __syncthreads();
    int wo = 0;
#pragma unroll
    for (int i = 0; i < 4; ++i) if (i < wv) wo += shm[128 + i];
    int excl = p.bsum[bx] + wo + (x - s);
    int pr[4];
    pr[0] = excl; pr[1] = pr[0] + c0; pr[2] = pr[1] + c1; pr[3] = pr[2] + c2;
#pragma unroll
    for (int j = 0; j < 4; ++j) {
      int idx = base + j;
      if (idx <= p.N) p.rp[idx] = pr[j];
      if (idx < p.N) p.cntp[idx * cs] = pr[j];   // wp aliases cnt
    }
  }
  gg.sync();
  // ---- P3: CSR build (padded atomic append)
  for (int e = tid; e < p.E; e += NT) {
    int d = p.edst[e];
    int pos = atomicAdd(&p.cntp[d * cs], 1);
    p.ep[pos] = make_int2(p.esrc[e], __float_as_int(p.ew[e]));
  }
  gg.sync();
  // ---- P4: gather layer 1 (wave-per-node, grid-stride)
  {
    int wid = tid >> 6, nw = NT >> 6, lane = t & 63;
    for (int n = wid; n < p.N; n += nw)
      gather1_node(n, lane, p.gnnh, p.rp, p.ep, p.g1xh);
  }
  gg.sync();
  // ---- P5: gather layer 2 + average (flagged nodes only)
  {
    int wid = tid >> 6, nw = NT >> 6, lane = t & 63;
    for (int n = wid; n < p.N; n += nw)
      if (p.flags[n])
        gatheravg_node(n, lane, p.g1xh, p.rp, p.ep, p.gnn, p.avgh);
  }
}

// ---------------------------------------------------------------------------
// Fallback multi-kernel path (R13 structure, strided counters)
// ---------------------------------------------------------------------------
__global__ void cvt_hist(const float* __restrict__ in, unsigned* __restrict__ out,
                         int n32, const int* __restrict__ dst, int* __restrict__ cntp,
                         int cs, int E, const int* __restrict__ seq,
                         unsigned char* __restrict__ flags, int BS) {
  int i = blockIdx.x * blockDim.x + threadIdx.x;
  if (i < n32) {
    float2 f = ((const float2*)in)[i];
    out[i] = packb(f.x, f.y);
  }
  if (i < E) atomicAdd(&cntp[dst[i] * cs], 1);
  if (i < BS) flags[seq[i]] = 1;
}

__global__ void gnn_chunk_sums(const int* __restrict__ cntp, int cs,
                               int* __restrict__ bsum) {
  __shared__ int ssum;
  if (threadIdx.x == 0) ssum = 0;
  __syncthreads();
  int base = blockIdx.x * 1024 + threadIdx.x * 4;
  int s = cntp[base * cs] + cntp[(base + 1) * cs] + cntp[(base + 2) * cs] +
          cntp[(base + 3) * cs];
#pragma unroll
  for (int o = 32; o > 0; o >>= 1) s += __shfl_xor(s, o, 64);
  if ((threadIdx.x & 63) == 0) atomicAdd(&ssum, s);
  __syncthreads();
  if (threadIdx.x == 0) bsum[blockIdx.x] = ssum;
}

__global__ void gnn_scan_bsum(int* __restrict__ bsum, int nch) {
  __shared__ int sb[128];
  int t = threadIdx.x;
  if (t < nch) sb[t] = bsum[t];
  __syncthreads();
  if (t == 0) {
    int a = 0;
    for (int i = 0; i < nch; ++i) { int v = sb[i]; sb[i] = a; a += v; }
  }
  __syncthreads();
  if (t < nch) bsum[t] = sb[t];
}

__global__ void gnn_chunk_scan(const int* __restrict__ cntp_in, int cs,
                               const int* __restrict__ bofs,
                               int* __restrict__ rp, int* __restrict__ cntp,
                               int Nn) {
  __shared__ int wsum[4];
  int t = threadIdx.x, lane = t & 63, wv = t >> 6;
  int base = blockIdx.x * 1024 + t * 4;
  int c0 = cntp_in[base * cs], c1 = cntp_in[(base + 1) * cs];
  int c2 = cntp_in[(base + 2) * cs], c3 = cntp_in[(base + 3) * cs];
  int s = c0 + c1 + c2 + c3;
  int x = s;
#pragma unroll
  for (int o = 1; o < 64; o <<= 1) {
    int y = __shfl_up(x, o, 64);
    if (lane >= o) x += y;
  }
  if (lane == 63) wsum[wv] = x;
  __syncthreads();
  int wo = 0;
#pragma unroll
  for (int i = 0; i < 4; ++i) if (i < wv) wo += wsum[i];
  int excl = bofs[blockIdx.x] + wo + (x - s);
  int p[4];
  p[0] = excl; p[1] = p[0] + c0; p[2] = p[1] + c1; p[3] = p[2] + c2;
#pragma unroll
  for (int j = 0; j < 4; ++j) {
    int idx = base + j;
    if (idx <= Nn) rp[idx] = p[j];
    if (idx < Nn) cntp[idx * cs] = p[j];
  }
}

__global__ void gnn_build(const int* __restrict__ src, const int* __restrict__ dst,
                          const float* __restrict__ ew, int* __restrict__ cntp,
                          int cs, int2* __restrict__ ep, int E) {
  int e = blockIdx.x * blockDim.x + threadIdx.x;
  if (e >= E) return;
  int pos = atomicAdd(&cntp[dst[e] * cs], 1);
  ep[pos] = make_int2(src[e], __float_as_int(ew[e]));
}

__global__ void gnn_gather1(const unsigned* __restrict__ xinh,
                            const int* __restrict__ rp, const int2* __restrict__ ep,
                            unsigned* __restrict__ xouth, int Nn) {
  int n = blockIdx.x * 4 + (threadIdx.x >> 6);
  if (n >= Nn) return;
  gather1_node(n, threadIdx.x & 63, xinh, rp, ep, xouth);
}

__global__ void gnn_gather_avg(const unsigned* __restrict__ x1h,
                               const int* __restrict__ rp, const int2* __restrict__ ep,
                               const float* __restrict__ gnn,
                               unsigned* __restrict__ avgh, int Nn,
                               const unsigned char* __restrict__ flags) {
  int n = blockIdx.x * 4 + (threadIdx.x >> 6);
  if (n >= Nn) return;
  if (!flags[n]) return;
  gatheravg_node(n, threadIdx.x & 63, x1h, rp, ep, gnn, avgh);
}

// fp32 scatter fallback helpers
__global__ void gnn_scatter(const float* __restrict__ xin,
                            const int* __restrict__ src,
                            const int* __restrict__ dst,
                            const float* __restrict__ ew,
                            float* __restrict__ xout, int E) {
  int gid = blockIdx.x * blockDim.x + threadIdx.x;
  int e = gid >> 6;
  int d = gid & 63;
  if (e >= E) return;
  atomicAdd(&xout[(size_t)dst[e] * SD + d], xin[(size_t)src[e] * SD + d] * ew[e]);
}
__global__ void avg_from_f32(const float* __restrict__ gnn, const float* __restrict__ g1,
                             const float* __restrict__ g2, unsigned* __restrict__ avgh,
                             int n32) {
  int i = blockIdx.x * blockDim.x + threadIdx.x;
  if (i >= n32) return;
  float2 a = ((const float2*)gnn)[i];
  float2 b = ((const float2*)g1)[i];
  float2 c = ((const float2*)g2)[i];
  avgh[i] = packb((a.x + b.x + c.x) * (1.f / 3.f), (a.y + b.y + c.y) * (1.f / 3.f));
}

// ---------------------------------------------------------------------------
// MFMA transformer, row-ownership version (unchanged from R12/R13).
// ---------------------------------------------------------------------------
__global__ __launch_bounds__(256, 3)
void seq_transformer(const int* __restrict__ seq, const int* __restrict__ lengths,
                     const float* __restrict__ bert, const short* __restrict__ avgh,
                     const float* __restrict__ pbias, const float* __restrict__ pos,
                     const short* __restrict__ pwB, const short* __restrict__ wqB,
                     const short* __restrict__ wkB, const short* __restrict__ wvB,
                     const short* __restrict__ woB, const short* __restrict__ w1B,
                     const short* __restrict__ w2B,
                     const float* __restrict__ b1, const float* __restrict__ b2,
                     const float* __restrict__ ln1g, const float* __restrict__ ln1b,
                     const float* __restrict__ ln2g, const float* __restrict__ ln2b,
                     const float* __restrict__ lnfg, const float* __restrict__ lnfb,
                     float* __restrict__ out) {
  __shared__ short xh[64 * PH];
  __shared__ short qh[64 * PH];
  __shared__ short kh[64 * PH];
  __shared__ short vt[64 * PH];
  __shared__ short s0[64 * PH];
  __shared__ int   sidx[64];

  const int t = threadIdx.x;
  const int lane = t & 63;
  const int mt = t >> 6;
  const int quad = lane >> 4;
  const int c0 = lane & 15;
  const int b = blockIdx.x;
  const int arow = mt * 16 + c0;

  if (t < 64) sidx[t] = (t < SS) ? seq[b * SS + t] : 0;
  __syncthreads();

  const int len = lengths[b];
  const float alpha = (len <= 10) ? 0.3f : ((len >= 50) ? 0.7f : 0.5f);
  const float isq = 0.17677669529663687f;

  float kbias[4];
#pragma unroll
  for (int nt = 0; nt < 4; ++nt) {
    int key = nt * 16 + c0;
    kbias[nt] = (key < SS && sidx[key] != 0) ? 0.f : -1e9f;
  }

#pragma unroll
  for (int ir = 0; ir < 16; ++ir) {
    int s = mt * 16 + ir;
    short v = 0;
    if (s < SS) v = avgh[(size_t)sidx[s] * SD + lane];
    qh[s * PH + lane] = v;
  }

  {
    f32x4 o4[4];
    mm64(qh, pwB, arow, quad, lane, o4);
#pragma unroll
    for (int nt = 0; nt < 4; ++nt) {
      int c = nt * 16 + c0;
      float pbv = pbias[c];
#pragma unroll
      for (int r = 0; r < 4; ++r) {
        int row = mt * 16 + quad * 4 + r;
        short ov = 0;
        if (row < SS) {
          float g = o4[nt][r] + pbv;
          float xv = alpha * bert[(size_t)sidx[row] * SD + c] +
                     (1.f - alpha) * g + pos[row * SD + c];
          ov = f2b(xv);
        }
        xh[row * PH + c] = ov;
      }
    }
  }

#pragma unroll 1
  for (int blk = 0; blk < NBLK; ++blk) {
    const short* Wq = wqB + blk * 4096;
    const short* Wk = wkB + blk * 4096;
    const short* Wv = wvB + blk * 4096;
    const short* Wo = woB + blk * 4096;
    const short* W1 = w1B + blk * 16384;
    const short* W2 = w2B + blk * 16384;

    __syncthreads();

    {
      f32x4 o4[4];
      mm64(xh, Wq, arow, quad, lane, o4);
#pragma unroll
      for (int nt = 0; nt < 4; ++nt) {
        int c = nt * 16 + c0;
#pragma unroll
        for (int r = 0; r < 4; ++r) qh[(mt * 16 + quad * 4 + r) * PH + c] = f2b(o4[nt][r]);
      }
      mm64(xh, Wk, arow, quad, lane, o4);
#pragma unroll
      for (int nt = 0; nt < 4; ++nt) {
        int c = nt * 16 + c0;
#pragma unroll
        for (int r = 0; r < 4; ++r) kh[(mt * 16 + quad * 4 + r) * PH + c] = f2b(o4[nt][r]);
      }
      mm64(xh, Wv, arow, quad, lane, o4);
#pragma unroll
      for (int nt = 0; nt < 4; ++nt) {
        int dim = nt * 16 + c0;
        unsigned p0 = packb(o4[nt][0], o4[nt][1]);
        unsigned p1 = packb(o4[nt][2], o4[nt][3]);
        *(uint2*)(vt + (size_t)dim * PH + mt * 16 + quad * 4) = make_uint2(p0, p1);
      }
    }
    __syncthreads();

#pragma unroll
    for (int h = 0; h < 2; ++h) {
      {
        bf16x8 aq = *(const bf16x8*)(qh + arow * PH + h * 32 + quad * 8);
        float p[4][4];
        float mx[4], sm[4];
#pragma unroll
        for (int nt = 0; nt < 4; ++nt) {
          int key = nt * 16 + c0;
          bf16x8 bk = *(const bf16x8*)(kh + key * PH + h * 32 + quad * 8);
          f32x4 acc = {0.f, 0.f, 0.f, 0.f};
          acc = __builtin_amdgcn_mfma_f32_16x16x32_bf16(aq, bk, acc, 0, 0, 0);
#pragma unroll
          for (int r = 0; r < 4; ++r) p[nt][r] = fmaf(acc[r], isq, kbias[nt]);
        }
#pragma unroll
        for (int r = 0; r < 4; ++r)
          mx[r] = fmaxf(fmaxf(p[0][r], p[1][r]), fmaxf(p[2][r], p[3][r]));
#pragma unroll
        for (int o = 1; o < 16; o <<= 1)
#pragma unroll
          for (int r = 0; r < 4; ++r) mx[r] = fmaxf(mx[r], __shfl_xor(mx[r], o, 64));
#pragma unroll
        for (int r = 0; r < 4; ++r) sm[r] = 0.f;
#pragma unroll
        for (int nt = 0; nt < 4; ++nt)
#pragma unroll
          for (int r = 0; r < 4; ++r) {
            float e = __expf(p[nt][r] - mx[r]);
            p[nt][r] = e;
            sm[r] += e;
          }
#pragma unroll
        for (int o = 1; o < 16; o <<= 1)
#pragma unroll
          for (int r = 0; r < 4; ++r) sm[r] += __shfl_xor(sm[r], o, 64);
#pragma unroll
        for (int r = 0; r < 4; ++r) {
          float inv = __builtin_amdgcn_rcpf(sm[r]);
          int q = mt * 16 + quad * 4 + r;
#pragma unroll
          for (int nt = 0; nt < 4; ++nt)
            s0[q * PH + nt * 16 + c0] = f2b(p[nt][r] * inv);
        }
      }
      {
        bf16x8 a0 = *(const bf16x8*)(s0 + arow * PH + quad * 8);
        bf16x8 a1 = *(const bf16x8*)(s0 + arow * PH + 32 + quad * 8);
#pragma unroll
        for (int nt = 0; nt < 2; ++nt) {
          int dim = h * 32 + nt * 16 + c0;
          bf16x8 b0 = *(const bf16x8*)(vt + (size_t)dim * PH + quad * 8);
          bf16x8 b1v = *(const bf16x8*)(vt + (size_t)dim * PH + 32 + quad * 8);
          f32x4 acc = {0.f, 0.f, 0.f, 0.f};
          acc = __builtin_amdgcn_mfma_f32_16x16x32_bf16(a0, b0, acc, 0, 0, 0);
          acc = __builtin_amdgcn_mfma_f32_16x16x32_bf16(a1, b1v, acc, 0, 0, 0);
#pragma unroll
          for (int r = 0; r < 4; ++r)
            qh[(mt * 16 + quad * 4 + r) * PH + dim] = f2b(acc[r]);
        }
      }
    }

    {
      f32x4 o4[4];
      mm64(qh, Wo, arow, quad, lane, o4);
      ln_epilogue(o4, xh, ln1g + blk * SD, ln1b + blk * SD, nullptr, mt, quad, c0);
    }

    f32x4 facc[4];
#pragma unroll
    for (int nt = 0; nt < 4; ++nt) facc[nt] = (f32x4){0.f, 0.f, 0.f, 0.f};
#pragma unroll 1
    for (int c = 0; c < 4; ++c) {
      {
        bf16x8 a0 = *(const bf16x8*)(xh + arow * PH + quad * 8);
        bf16x8 a1 = *(const bf16x8*)(xh + arow * PH + 32 + quad * 8);
#pragma unroll
        for (int nt = 0; nt < 4; ++nt) {
          int ntg = c * 4 + nt;
          f32x4 acc = {0.f, 0.f, 0.f, 0.f};
          acc = __builtin_amdgcn_mfma_f32_16x16x32_bf16(a0, ldB(W1, 0 * 16 + ntg, lane), acc, 0, 0, 0);
          acc = __builtin_amdgcn_mfma_f32_16x16x32_bf16(a1, ldB(W1, 1 * 16 + ntg, lane), acc, 0, 0, 0);
          int cc = nt * 16 + c0;
          float b1v = b1[blk * 256 + c * 64 + cc];
#pragma unroll
          for (int r = 0; r < 4; ++r)
            qh[(mt * 16 + quad * 4 + r) * PH + cc] = f2b(gelu_fast(acc[r] + b1v));
        }
      }
      {
        bf16x8 a0 = *(const bf16x8*)(qh + arow * PH + quad * 8);
        bf16x8 a1 = *(const bf16x8*)(qh + arow * PH + 32 + quad * 8);
#pragma unroll
        for (int nt = 0; nt < 4; ++nt) {
          facc[nt] = __builtin_amdgcn_mfma_f32_16x16x32_bf16(a0, ldB(W2, (2 * c) * 4 + nt, lane), facc[nt], 0, 0, 0);
          facc[nt] = __builtin_amdgcn_mfma_f32_16x16x32_bf16(a1, ldB(W2, (2 * c + 1) * 4 + nt, lane), facc[nt], 0, 0, 0);
        }
      }
    }

    ln_epilogue(facc, xh, ln2g + blk * SD, ln2b + blk * SD, b2 + blk * SD, mt, quad, c0);
  }
  __syncthreads();

  if (mt == 0) {
    int sl = len - 1;
    float val = b2f(xh[sl * PH + lane]);
    float2 ss = wred_sum2(val, val * val);
    float m = ss.x * (1.f / 64);
    float var = fmaxf(ss.y * (1.f / 64) - m * m, 0.f);
    float rs = rsqrtf(var + 1e-5f);
    out[b * SD + lane] = (val - m) * rs * lnfg[lane] + lnfb[lane];
  }
}

// ---------------------------------------------------------------------------
extern "C" void kernel_launch(void* const* d_in, const int* in_sizes, int n_in,
                              void* d_out, int out_size, void* d_ws, size_t ws_size,
                              hipStream_t stream) {
  const int*   seq   = (const int*)d_in[0];
  const int*   lens  = (const int*)d_in[1];
  const int*   ei    = (const int*)d_in[2];
  const float* ew    = (const float*)d_in[3];
  const float* bert  = (const float*)d_in[4];
  const float* gnn   = (const float*)d_in[5];
  const float* pw    = (const float*)d_in[6];
  const float* pb    = (const float*)d_in[7];
  const float* pos   = (const float*)d_in[8];
  const float* wq    = (const float*)d_in[9];
  const float* wk    = (const float*)d_in[10];
  const float* wv    = (const float*)d_in[11];
  const float* wo    = (const float*)d_in[12];
  const float* w1    = (const float*)d_in[13];
  const float* b1    = (const float*)d_in[14];
  const float* w2    = (const float*)d_in[15];
  const float* b2    = (const float*)d_in[16];
  const float* ln1g  = (const float*)d_in[17];
  const float* ln1b  = (const float*)d_in[18];
  const float* ln2g  = (const float*)d_in[19];
  const float* ln2b  = (const float*)d_in[20];
  const float* lnfg  = (const float*)d_in[21];
  const float* lnfb  = (const float*)d_in[22];
  float* out = (float*)d_out;

  const int E = in_sizes[2] / 2;          // 1,000,000
  const int B = in_sizes[0] / SS;         // 1024
  const int N = in_sizes[4] / SD;         // 100,001
  const int BS = B * SS;                  // 51,200

  const int* esrc = ei;
  const int* edst = ei + E;

  const int NCH = (N + 1023) >> 10;
  const int NF = (N + 15) & ~15;
  const int n32 = N * 32;

  // ---- workspace layout (counter stride cs chosen to fit)
  short* pwB; short* wqB; short* wkB; short* wvB; short* woB; short* w1B; short* w2B;
  unsigned* gnnh; unsigned* g1xh; unsigned* avgh;
  int* cntp; unsigned char* flags; int* bsum; int* rp; int2* ep;
  size_t need = 0;
  int cs = 16;
  auto layout = [&](int cstride) -> size_t {
    pwB = (short*)d_ws;
    wqB = pwB + 4096;
    wkB = wqB + 8192;
    wvB = wkB + 8192;
    woB = wvB + 8192;
    w1B = woB + 8192;
    w2B = w1B + 32768;
    gnnh = (unsigned*)(w2B + 32768);
    g1xh = gnnh + (size_t)N * 32;
    avgh = g1xh + (size_t)N * 32;
    cntp = (int*)(avgh + (size_t)N * 32);
    flags = (unsigned char*)(cntp + (size_t)(NCH << 10) * cstride);
    bsum = (int*)(flags + NF);
    rp = bsum + 128;
    ep = (int2*)((((size_t)(rp + N + 1)) + 15) & ~(size_t)15);
    return (size_t)((char*)(ep + E) - (char*)d_ws);
  };
  need = layout(16); cs = 16;
  if (need > ws_size) { need = layout(4); cs = 4; }
  if (need > ws_size) { need = layout(1); cs = 1; }

  // fp32 fallback tables (overlay the counter region)
  float* g1x = (float*)cntp;
  float* g2x = g1x + (size_t)N * SD;
  size_t need_fb = (size_t)((char*)(g2x + (size_t)N * SD) - (char*)d_ws);

  if (need <= ws_size && NCH <= 128) {
    GP P;
    P.gnn = gnn; P.seq = seq; P.esrc = esrc; P.edst = edst; P.ew = ew;
    P.pw = pw; P.wq = wq; P.wk = wk; P.wv = wv; P.wo = wo; P.w1 = w1; P.w2 = w2;
    P.pwB = pwB; P.wqB = wqB; P.wkB = wkB; P.wvB = wvB; P.woB = woB;
    P.w1B = w1B; P.w2B = w2B;
    P.gnnh = gnnh; P.g1xh = g1xh; P.avgh = avgh;
    P.cntp = cntp; P.flags = flags; P.bsum = bsum; P.rp = rp; P.ep = ep;
    P.N = N; P.E = E; P.BS = BS; P.NCH = NCH; P.cs = cs; P.n32 = n32;
    P.nfw = NF / 4;
    void* args[] = {(void*)&P};
    hipError_t err = hipLaunchCooperativeKernel((void*)gnn_all, dim3(GRID),
                                                dim3(256), args, 0, stream);
    if (err != hipSuccess) {
      // fallback: R13 multi-kernel path (same layout, strided counters)
      prep_all<<<50, 256, 0, stream>>>(pw, wq, wk, wv, wo, w1, w2,
                                       pwB, wqB, wkB, wvB, woB, w1B, w2B);
      hipMemsetAsync(cntp, 0, (size_t)(NCH << 10) * cs * sizeof(int) + NF, stream);
      cvt_hist<<<(n32 + 255) / 256, 256, 0, stream>>>(gnn, gnnh, n32, edst, cntp,
                                                      cs, E, seq, flags, BS);
      gnn_chunk_sums<<<NCH, 256, 0, stream>>>(cntp, cs, bsum);
      gnn_scan_bsum<<<1, 128, 0, stream>>>(bsum, NCH);
      gnn_chunk_scan<<<NCH, 256, 0, stream>>>(cntp, cs, bsum, rp, cntp, N);
      gnn_build<<<(E + 255) / 256, 256, 0, stream>>>(esrc, edst, ew, cntp, cs, ep, E);
      const int nb = (N + 3) / 4;
      gnn_gather1<<<nb, 256, 0, stream>>>(gnnh, rp, ep, g1xh, N);
      gnn_gather_avg<<<nb, 256, 0, stream>>>(g1xh, rp, ep, gnn, avgh, N, flags);
    }
  } else if (ws_size >= need_fb) {
    prep_all<<<50, 256, 0, stream>>>(pw, wq, wk, wv, wo, w1, w2,
                                     pwB, wqB, wkB, wvB, woB, w1B, w2B);
    hipMemsetAsync(g1x, 0, (size_t)2 * N * SD * sizeof(float), stream);
    const long total = (long)E * 64;
    const int sblocks = (int)((total + 255) / 256);
    gnn_scatter<<<sblocks, 256, 0, stream>>>(gnn, esrc, edst, ew, g1x, E);
    gnn_scatter<<<sblocks, 256, 0, stream>>>(g1x, esrc, edst, ew, g2x, E);
    // convert gnn table to bf16 pairs for the transformer path consistency
    avg_from_f32<<<(n32 + 255) / 256, 256, 0, stream>>>(gnn, g1x, g2x, avgh, n32);
  }

  seq_transformer<<<B, 256, 0, stream>>>(
      seq, lens, bert, (const short*)avgh, pb, pos,
      pwB, wqB, wkB, wvB, woB, w1B, w2B,
      b1, b2, ln1g, ln1b, ln2g, ln2b, lnfg, lnfb, out);
}

// Round 5
// 384.249 us; speedup vs baseline: 3.2108x; 3.2108x over previous
//
#include <hip/hip_runtime.h>
#include <math.h>

// ---------------------------------------------------------------------------
// HybridBERT4RecGNN forward on MI355X (gfx950), round 16.
//
// R14: coop mega-kernel = 1025us disaster (coherent-path + L2 kill). R15
// (chained-scan spin-wait) -> container failed twice; spin-wait is the
// suspect and is now banned (guide G16: no dispatch-timing dependence).
// R16 = R13 (proven 377us) + the SAFE subset of R15:
//  (a) prep_zero = weight prep + counter/flag zeroing in one kernel
//      (replaces hipMemsetAsync + prep_all; no cross-block deps).
//  (b) atomic counters padded to 1 per 64B line (cs=16, fallback 4/1) in
//      cvt_hist histogram + gnn_build append -- removes 16-per-line
//      serialization at the memory-side atomic units.
//  (c) R13's proven 3-kernel scan, cs-strided.
// 10 -> 8 dispatches, zero unproven sync constructs.
// ---------------------------------------------------------------------------

typedef __attribute__((ext_vector_type(8))) short bf16x8;
typedef __attribute__((ext_vector_type(4))) float f32x4;

#define SD   64
#define SS   50
#define NBLK 2
#define PH   72    // LDS pitch in halves (144 B, 16B-aligned rows, 2-way banks max)

__device__ __forceinline__ short f2b(float f) {  // fp32 -> bf16 RNE (HW cvt)
  union { __bf16 h; short s; } u;
  u.h = (__bf16)f;
  return u.s;
}
__device__ __forceinline__ float b2f(short s) {
  union { unsigned u; float f; } v;
  v.u = ((unsigned)(unsigned short)s) << 16;
  return v.f;
}
__device__ __forceinline__ unsigned packb(float a, float b) {
  union { __bf16 h; unsigned short s; } ua, ub;
  ua.h = (__bf16)a; ub.h = (__bf16)b;
  return (unsigned)ua.s | ((unsigned)ub.s << 16);
}
__device__ __forceinline__ float2 wred_sum2(float a, float b) {
#pragma unroll
  for (int o = 32; o > 0; o >>= 1) {
    a += __shfl_xor(a, o, 64);
    b += __shfl_xor(b, o, 64);
  }
  return make_float2(a, b);
}
// gelu(x) = 0.5x(1+tanh(u)) = x * sigmoid(2u);  sigmoid via v_rcp_f32.
__device__ __forceinline__ float gelu_fast(float x) {
  float u = 0.7978845608028654f * x * (1.0f + 0.044715f * x * x);
  float e = __expf(-2.f * u);
  return x * __builtin_amdgcn_rcpf(1.0f + e);
}

__device__ __forceinline__ bf16x8 ldB(const short* __restrict__ Wb, int tile, int lane) {
  return *(const bf16x8*)(Wb + ((size_t)tile * 64 + lane) * 8);
}

// [own 16 rows x K=64] @ [64x64] -> D own rows. A from LDS bf16 pitch PH.
__device__ __forceinline__ void mm64(const short* A, const short* __restrict__ Wb,
                                     int arow, int quad, int lane, f32x4 o4[4]) {
  bf16x8 a0 = *(const bf16x8*)(A + arow * PH + quad * 8);
  bf16x8 a1 = *(const bf16x8*)(A + arow * PH + 32 + quad * 8);
#pragma unroll
  for (int nt = 0; nt < 4; ++nt) {
    f32x4 acc = {0.f, 0.f, 0.f, 0.f};
    acc = __builtin_amdgcn_mfma_f32_16x16x32_bf16(a0, ldB(Wb, 0 * 4 + nt, lane), acc, 0, 0, 0);
    acc = __builtin_amdgcn_mfma_f32_16x16x32_bf16(a1, ldB(Wb, 1 * 4 + nt, lane), acc, 0, 0, 0);
    o4[nt] = acc;
  }
}

// LN over 64 cols of D-layout values + residual from xh + optional bias.
__device__ __forceinline__ void ln_epilogue(f32x4 o4[4], short* xh,
                                            const float* __restrict__ g,
                                            const float* __restrict__ bta,
                                            const float* __restrict__ extrab,
                                            int mt, int quad, int c0) {
  float vals[4][4];
  float s1[4] = {0.f, 0.f, 0.f, 0.f}, s2[4] = {0.f, 0.f, 0.f, 0.f};
#pragma unroll
  for (int nt = 0; nt < 4; ++nt) {
    int c = nt * 16 + c0;
    float eb = extrab ? extrab[c] : 0.f;
#pragma unroll
    for (int r = 0; r < 4; ++r) {
      int row = mt * 16 + quad * 4 + r;
      float v = o4[nt][r] + b2f(xh[row * PH + c]) + eb;
      vals[nt][r] = v;
      s1[r] += v;
      s2[r] += v * v;
    }
  }
#pragma unroll
  for (int o = 1; o < 16; o <<= 1) {
#pragma unroll
    for (int r = 0; r < 4; ++r) {
      s1[r] += __shfl_xor(s1[r], o, 64);
      s2[r] += __shfl_xor(s2[r], o, 64);
    }
  }
  float mv[4], rv[4];
#pragma unroll
  for (int r = 0; r < 4; ++r) {
    float m = s1[r] * (1.f / 64);
    float var = fmaxf(s2[r] * (1.f / 64) - m * m, 0.f);
    mv[r] = m;
    rv[r] = rsqrtf(var + 1e-5f);
  }
#pragma unroll
  for (int nt = 0; nt < 4; ++nt) {
    int c = nt * 16 + c0;
    float gv = g[c], bv = bta[c];
#pragma unroll
    for (int r = 0; r < 4; ++r) {
      int row = mt * 16 + quad * 4 + r;
      xh[row * PH + c] = f2b((vals[nt][r] - mv[r]) * rv[r] * gv + bv);
    }
  }
}

// ---------------------------------------------------------------------------
// Weight prep body
// ---------------------------------------------------------------------------
__device__ __forceinline__ void prep_body(int tid,
    const float* __restrict__ pw, const float* __restrict__ wq,
    const float* __restrict__ wk, const float* __restrict__ wv,
    const float* __restrict__ wo, const float* __restrict__ w1,
    const float* __restrict__ w2,
    short* __restrict__ pwB, short* __restrict__ wqB,
    short* __restrict__ wkB, short* __restrict__ wvB,
    short* __restrict__ woB, short* __restrict__ w1B,
    short* __restrict__ w2B) {
  int lane = tid & 63;
  int tile = tid >> 6;
  const float* W; short* out; int K, N, base;
  if (tile < 8)        { W = pw; out = pwB; K = 64;  N = 64;  base = 0; }
  else if (tile < 24)  { W = wq; out = wqB; K = 64;  N = 64;  base = 8; }
  else if (tile < 40)  { W = wk; out = wkB; K = 64;  N = 64;  base = 24; }
  else if (tile < 56)  { W = wv; out = wvB; K = 64;  N = 64;  base = 40; }
  else if (tile < 72)  { W = wo; out = woB; K = 64;  N = 64;  base = 56; }
  else if (tile < 136) { W = w1; out = w1B; K = 64;  N = 256; base = 72; }
  else if (tile < 200) { W = w2; out = w2B; K = 256; N = 64;  base = 136; }
  else return;
  int lt = tile - base;
  int KT = K / 32, NT = N / 16;
  int nt = lt % NT; lt /= NT;
  int kt = lt % KT; lt /= KT;
  int m = lt;
  const float* Wm = W + (size_t)m * K * N;
  int kbase = kt * 32 + ((lane >> 4) * 8);
  int n = nt * 16 + (lane & 15);
  short v[8];
#pragma unroll
  for (int j = 0; j < 8; ++j) v[j] = f2b(Wm[(size_t)(kbase + j) * N + n]);
  *(bf16x8*)(out + ((size_t)(tile - base) * 64 + lane) * 8) = *(bf16x8*)v;
}

// Weight prep + zero counters/flags (replaces memset + prep_all).
__global__ void prep_zero(const float* __restrict__ pw, const float* __restrict__ wq,
                          const float* __restrict__ wk, const float* __restrict__ wv,
                          const float* __restrict__ wo, const float* __restrict__ w1,
                          const float* __restrict__ w2,
                          short* __restrict__ pwB, short* __restrict__ wqB,
                          short* __restrict__ wkB, short* __restrict__ wvB,
                          short* __restrict__ woB, short* __restrict__ w1B,
                          short* __restrict__ w2B,
                          int* __restrict__ cntp, int cntn,
                          int* __restrict__ flagsw, int nfw) {
  int tid = blockIdx.x * blockDim.x + threadIdx.x;
  int NT = gridDim.x * blockDim.x;
  prep_body(tid, pw, wq, wk, wv, wo, w1, w2, pwB, wqB, wkB, wvB, woB, w1B, w2B);
  for (int i = tid; i < cntn; i += NT) cntp[i] = 0;
  for (int i = tid; i < nfw; i += NT) flagsw[i] = 0;
}

// fp32 table -> packed bf16 pairs, fused with dst-degree histogram (padded
// counters) and seq-referenced-node flagging.
__global__ void cvt_hist(const float* __restrict__ in, unsigned* __restrict__ out,
                         int n32, const int* __restrict__ dst, int* __restrict__ cntp,
                         int cs, int E, const int* __restrict__ seq,
                         unsigned char* __restrict__ flags, int BS) {
  int i = blockIdx.x * blockDim.x + threadIdx.x;
  if (i < n32) {
    float2 f = ((const float2*)in)[i];
    out[i] = packb(f.x, f.y);
  }
  if (i < E) atomicAdd(&cntp[dst[i] * cs], 1);
  if (i < BS) flags[seq[i]] = 1;
}

// ---------------------------------------------------------------------------
// GNN CSR scan (R13-proven 3-kernel structure, cs-strided counters)
// ---------------------------------------------------------------------------
__global__ void gnn_chunk_sums(const int* __restrict__ cntp, int cs,
                               int* __restrict__ bsum) {
  __shared__ int ssum;
  if (threadIdx.x == 0) ssum = 0;
  __syncthreads();
  int base = blockIdx.x * 1024 + threadIdx.x * 4;
  int s = cntp[base * cs] + cntp[(base + 1) * cs] + cntp[(base + 2) * cs] +
          cntp[(base + 3) * cs];
#pragma unroll
  for (int o = 32; o > 0; o >>= 1) s += __shfl_xor(s, o, 64);
  if ((threadIdx.x & 63) == 0) atomicAdd(&ssum, s);
  __syncthreads();
  if (threadIdx.x == 0) bsum[blockIdx.x] = ssum;
}

__global__ void gnn_scan_bsum(int* __restrict__ bsum, int nch) {
  __shared__ int sb[128];
  int t = threadIdx.x;
  if (t < nch) sb[t] = bsum[t];
  __syncthreads();
  if (t == 0) {
    int a = 0;
    for (int i = 0; i < nch; ++i) { int v = sb[i]; sb[i] = a; a += v; }
  }
  __syncthreads();
  if (t < nch) bsum[t] = sb[t];
}

__global__ void gnn_chunk_scan(const int* __restrict__ cntp_in, int cs,
                               const int* __restrict__ bofs,
                               int* __restrict__ rp, int* __restrict__ cntp,
                               int Nn) {
  __shared__ int wsum[4];
  int t = threadIdx.x, lane = t & 63, wv = t >> 6;
  int base = blockIdx.x * 1024 + t * 4;
  int c0 = cntp_in[base * cs], c1 = cntp_in[(base + 1) * cs];
  int c2 = cntp_in[(base + 2) * cs], c3 = cntp_in[(base + 3) * cs];
  int s = c0 + c1 + c2 + c3;
  int x = s;
#pragma unroll
  for (int o = 1; o < 64; o <<= 1) {
    int y = __shfl_up(x, o, 64);
    if (lane >= o) x += y;
  }
  if (lane == 63) wsum[wv] = x;
  __syncthreads();
  int wo = 0;
#pragma unroll
  for (int i = 0; i < 4; ++i) if (i < wv) wo += wsum[i];
  int excl = bofs[blockIdx.x] + wo + (x - s);
  int p[4];
  p[0] = excl; p[1] = p[0] + c0; p[2] = p[1] + c1; p[3] = p[2] + c2;
#pragma unroll
  for (int j = 0; j < 4; ++j) {
    int idx = base + j;
    if (idx <= Nn) rp[idx] = p[j];
    if (idx < Nn) cntp[idx * cs] = p[j];   // wp aliases cnt
  }
}

__global__ void gnn_build(const int* __restrict__ src, const int* __restrict__ dst,
                          const float* __restrict__ ew, int* __restrict__ cntp,
                          int cs, int2* __restrict__ ep, int E) {
  int e = blockIdx.x * blockDim.x + threadIdx.x;
  if (e >= E) return;
  int pos = atomicAdd(&cntp[dst[e] * cs], 1);
  ep[pos] = make_int2(src[e], __float_as_int(ew[e]));
}

// ---------------------------------------------------------------------------
// Gather kernels, 8-slot wave-per-node (unchanged from R13).
// ---------------------------------------------------------------------------
__device__ __forceinline__ void gather1_node(int n, int lane,
    const unsigned* __restrict__ xinh, const int* __restrict__ rp,
    const int2* __restrict__ ep, unsigned* __restrict__ xouth) {
  int slot = lane >> 3;
  int g = lane & 7;
  int beg = rp[n], end = rp[n + 1];
  float a[8] = {0.f, 0.f, 0.f, 0.f, 0.f, 0.f, 0.f, 0.f};
  for (int e = beg + slot; e < end; e += 8) {
    int2 ee = ep[e];
    float w = __int_as_float(ee.y);
    uint4 p = *(const uint4*)(xinh + (size_t)ee.x * 32 + g * 4);
    a[0] += b2f((short)(p.x & 0xFFFF)) * w;
    a[1] += b2f((short)(p.x >> 16)) * w;
    a[2] += b2f((short)(p.y & 0xFFFF)) * w;
    a[3] += b2f((short)(p.y >> 16)) * w;
    a[4] += b2f((short)(p.z & 0xFFFF)) * w;
    a[5] += b2f((short)(p.z >> 16)) * w;
    a[6] += b2f((short)(p.w & 0xFFFF)) * w;
    a[7] += b2f((short)(p.w >> 16)) * w;
  }
#pragma unroll
  for (int o = 8; o < 64; o <<= 1)
#pragma unroll
    for (int j = 0; j < 8; ++j) a[j] += __shfl_xor(a[j], o, 64);
  if (slot == 0) {
    uint4 o4;
    o4.x = packb(a[0], a[1]);
    o4.y = packb(a[2], a[3]);
    o4.z = packb(a[4], a[5]);
    o4.w = packb(a[6], a[7]);
    *(uint4*)(xouth + (size_t)n * 32 + g * 4) = o4;
  }
}

__device__ __forceinline__ void gatheravg_node(int n, int lane,
    const unsigned* __restrict__ x1h, const int* __restrict__ rp,
    const int2* __restrict__ ep, const float* __restrict__ gnn,
    unsigned* __restrict__ avgh) {
  int slot = lane >> 3;
  int g = lane & 7;
  int beg = rp[n], end = rp[n + 1];
  float a[8] = {0.f, 0.f, 0.f, 0.f, 0.f, 0.f, 0.f, 0.f};
  for (int e = beg + slot; e < end; e += 8) {
    int2 ee = ep[e];
    float w = __int_as_float(ee.y);
    uint4 p = *(const uint4*)(x1h + (size_t)ee.x * 32 + g * 4);
    a[0] += b2f((short)(p.x & 0xFFFF)) * w;
    a[1] += b2f((short)(p.x >> 16)) * w;
    a[2] += b2f((short)(p.y & 0xFFFF)) * w;
    a[3] += b2f((short)(p.y >> 16)) * w;
    a[4] += b2f((short)(p.z & 0xFFFF)) * w;
    a[5] += b2f((short)(p.z >> 16)) * w;
    a[6] += b2f((short)(p.w & 0xFFFF)) * w;
    a[7] += b2f((short)(p.w >> 16)) * w;
  }
#pragma unroll
  for (int o = 8; o < 64; o <<= 1)
#pragma unroll
    for (int j = 0; j < 8; ++j) a[j] += __shfl_xor(a[j], o, 64);
  if (slot == 0) {
    uint4 own = *(const uint4*)(x1h + (size_t)n * 32 + g * 4);
    float4 g0 = *(const float4*)(gnn + (size_t)n * 64 + g * 8);
    float4 g1 = *(const float4*)(gnn + (size_t)n * 64 + g * 8 + 4);
    float v0 = (g0.x + b2f((short)(own.x & 0xFFFF)) + a[0]) * (1.f / 3.f);
    float v1 = (g0.y + b2f((short)(own.x >> 16)) + a[1]) * (1.f / 3.f);
    float v2 = (g0.z + b2f((short)(own.y & 0xFFFF)) + a[2]) * (1.f / 3.f);
    float v3 = (g0.w + b2f((short)(own.y >> 16)) + a[3]) * (1.f / 3.f);
    float v4 = (g1.x + b2f((short)(own.z & 0xFFFF)) + a[4]) * (1.f / 3.f);
    float v5 = (g1.y + b2f((short)(own.z >> 16)) + a[5]) * (1.f / 3.f);
    float v6 = (g1.z + b2f((short)(own.w & 0xFFFF)) + a[6]) * (1.f / 3.f);
    float v7 = (g1.w + b2f((short)(own.w >> 16)) + a[7]) * (1.f / 3.f);
    uint4 o4;
    o4.x = packb(v0, v1);
    o4.y = packb(v2, v3);
    o4.z = packb(v4, v5);
    o4.w = packb(v6, v7);
    *(uint4*)(avgh + (size_t)n * 32 + g * 4) = o4;
  }
}

__global__ void gnn_gather1(const unsigned* __restrict__ xinh,
                            const int* __restrict__ rp, const int2* __restrict__ ep,
                            unsigned* __restrict__ xouth, int Nn) {
  int n = blockIdx.x * 4 + (threadIdx.x >> 6);
  if (n >= Nn) return;
  gather1_node(n, threadIdx.x & 63, xinh, rp, ep, xouth);
}

__global__ void gnn_gather_avg(const unsigned* __restrict__ x1h,
                               const int* __restrict__ rp, const int2* __restrict__ ep,
                               const float* __restrict__ gnn,
                               unsigned* __restrict__ avgh, int Nn,
                               const unsigned char* __restrict__ flags) {
  int n = blockIdx.x * 4 + (threadIdx.x >> 6);
  if (n >= Nn) return;
  if (!flags[n]) return;
  gatheravg_node(n, threadIdx.x & 63, x1h, rp, ep, gnn, avgh);
}

// fp32 scatter fallback helpers
__global__ void gnn_scatter(const float* __restrict__ xin,
                            const int* __restrict__ src,
                            const int* __restrict__ dst,
                            const float* __restrict__ ew,
                            float* __restrict__ xout, int E) {
  int gid = blockIdx.x * blockDim.x + threadIdx.x;
  int e = gid >> 6;
  int d = gid & 63;
  if (e >= E) return;
  atomicAdd(&xout[(size_t)dst[e] * SD + d], xin[(size_t)src[e] * SD + d] * ew[e]);
}
__global__ void avg_from_f32(const float* __restrict__ gnn, const float* __restrict__ g1,
                             const float* __restrict__ g2, unsigned* __restrict__ avgh,
                             int n32) {
  int i = blockIdx.x * blockDim.x + threadIdx.x;
  if (i >= n32) return;
  float2 a = ((const float2*)gnn)[i];
  float2 b = ((const float2*)g1)[i];
  float2 c = ((const float2*)g2)[i];
  avgh[i] = packb((a.x + b.x + c.x) * (1.f / 3.f), (a.y + b.y + c.y) * (1.f / 3.f));
}

// ---------------------------------------------------------------------------
// MFMA transformer, row-ownership version (byte-identical to R12/R13).
// ---------------------------------------------------------------------------
__global__ __launch_bounds__(256, 3)
void seq_transformer(const int* __restrict__ seq, const int* __restrict__ lengths,
                     const float* __restrict__ bert, const short* __restrict__ avgh,
                     const float* __restrict__ pbias, const float* __restrict__ pos,
                     const short* __restrict__ pwB, const short* __restrict__ wqB,
                     const short* __restrict__ wkB, const short* __restrict__ wvB,
                     const short* __restrict__ woB, const short* __restrict__ w1B,
                     const short* __restrict__ w2B,
                     const float* __restrict__ b1, const float* __restrict__ b2,
                     const float* __restrict__ ln1g, const float* __restrict__ ln1b,
                     const float* __restrict__ ln2g, const float* __restrict__ ln2b,
                     const float* __restrict__ lnfg, const float* __restrict__ lnfb,
                     float* __restrict__ out) {
  __shared__ short xh[64 * PH];
  __shared__ short qh[64 * PH];
  __shared__ short kh[64 * PH];
  __shared__ short vt[64 * PH];
  __shared__ short s0[64 * PH];
  __shared__ int   sidx[64];

  const int t = threadIdx.x;
  const int lane = t & 63;
  const int mt = t >> 6;
  const int quad = lane >> 4;
  const int c0 = lane & 15;
  const int b = blockIdx.x;
  const int arow = mt * 16 + c0;

  if (t < 64) sidx[t] = (t < SS) ? seq[b * SS + t] : 0;
  __syncthreads();

  const int len = lengths[b];
  const float alpha = (len <= 10) ? 0.3f : ((len >= 50) ? 0.7f : 0.5f);
  const float isq = 0.17677669529663687f;

  float kbias[4];
#pragma unroll
  for (int nt = 0; nt < 4; ++nt) {
    int key = nt * 16 + c0;
    kbias[nt] = (key < SS && sidx[key] != 0) ? 0.f : -1e9f;
  }

#pragma unroll
  for (int ir = 0; ir < 16; ++ir) {
    int s = mt * 16 + ir;
    short v = 0;
    if (s < SS) v = avgh[(size_t)sidx[s] * SD + lane];
    qh[s * PH + lane] = v;
  }

  {
    f32x4 o4[4];
    mm64(qh, pwB, arow, quad, lane, o4);
#pragma unroll
    for (int nt = 0; nt < 4; ++nt) {
      int c = nt * 16 + c0;
      float pbv = pbias[c];
#pragma unroll
      for (int r = 0; r < 4; ++r) {
        int row = mt * 16 + quad * 4 + r;
        short ov = 0;
        if (row < SS) {
          float g = o4[nt][r] + pbv;
          float xv = alpha * bert[(size_t)sidx[row] * SD + c] +
                     (1.f - alpha) * g + pos[row * SD + c];
          ov = f2b(xv);
        }
        xh[row * PH + c] = ov;
      }
    }
  }

#pragma unroll 1
  for (int blk = 0; blk < NBLK; ++blk) {
    const short* Wq = wqB + blk * 4096;
    const short* Wk = wkB + blk * 4096;
    const short* Wv = wvB + blk * 4096;
    const short* Wo = woB + blk * 4096;
    const short* W1 = w1B + blk * 16384;
    const short* W2 = w2B + blk * 16384;

    __syncthreads();

    {
      f32x4 o4[4];
      mm64(xh, Wq, arow, quad, lane, o4);
#pragma unroll
      for (int nt = 0; nt < 4; ++nt) {
        int c = nt * 16 + c0;
#pragma unroll
        for (int r = 0; r < 4; ++r) qh[(mt * 16 + quad * 4 + r) * PH + c] = f2b(o4[nt][r]);
      }
      mm64(xh, Wk, arow, quad, lane, o4);
#pragma unroll
      for (int nt = 0; nt < 4; ++nt) {
        int c = nt * 16 + c0;
#pragma unroll
        for (int r = 0; r < 4; ++r) kh[(mt * 16 + quad * 4 + r) * PH + c] = f2b(o4[nt][r]);
      }
      mm64(xh, Wv, arow, quad, lane, o4);
#pragma unroll
      for (int nt = 0; nt < 4; ++nt) {
        int dim = nt * 16 + c0;
        unsigned p0 = packb(o4[nt][0], o4[nt][1]);
        unsigned p1 = packb(o4[nt][2], o4[nt][3]);
        *(uint2*)(vt + (size_t)dim * PH + mt * 16 + quad * 4) = make_uint2(p0, p1);
      }
    }
    __syncthreads();

#pragma unroll
    for (int h = 0; h < 2; ++h) {
      {
        bf16x8 aq = *(const bf16x8*)(qh + arow * PH + h * 32 + quad * 8);
        float p[4][4];
        float mx[4], sm[4];
#pragma unroll
        for (int nt = 0; nt < 4; ++nt) {
          int key = nt * 16 + c0;
          bf16x8 bk = *(const bf16x8*)(kh + key * PH + h * 32 + quad * 8);
          f32x4 acc = {0.f, 0.f, 0.f, 0.f};
          acc = __builtin_amdgcn_mfma_f32_16x16x32_bf16(aq, bk, acc, 0, 0, 0);
#pragma unroll
          for (int r = 0; r < 4; ++r) p[nt][r] = fmaf(acc[r], isq, kbias[nt]);
        }
#pragma unroll
        for (int r = 0; r < 4; ++r)
          mx[r] = fmaxf(fmaxf(p[0][r], p[1][r]), fmaxf(p[2][r], p[3][r]));
#pragma unroll
        for (int o = 1; o < 16; o <<= 1)
#pragma unroll
          for (int r = 0; r < 4; ++r) mx[r] = fmaxf(mx[r], __shfl_xor(mx[r], o, 64));
#pragma unroll
        for (int r = 0; r < 4; ++r) sm[r] = 0.f;
#pragma unroll
        for (int nt = 0; nt < 4; ++nt)
#pragma unroll
          for (int r = 0; r < 4; ++r) {
            float e = __expf(p[nt][r] - mx[r]);
            p[nt][r] = e;
            sm[r] += e;
          }
#pragma unroll
        for (int o = 1; o < 16; o <<= 1)
#pragma unroll
          for (int r = 0; r < 4; ++r) sm[r] += __shfl_xor(sm[r], o, 64);
#pragma unroll
        for (int r = 0; r < 4; ++r) {
          float inv = __builtin_amdgcn_rcpf(sm[r]);
          int q = mt * 16 + quad * 4 + r;
#pragma unroll
          for (int nt = 0; nt < 4; ++nt)
            s0[q * PH + nt * 16 + c0] = f2b(p[nt][r] * inv);
        }
      }
      {
        bf16x8 a0 = *(const bf16x8*)(s0 + arow * PH + quad * 8);
        bf16x8 a1 = *(const bf16x8*)(s0 + arow * PH + 32 + quad * 8);
#pragma unroll
        for (int nt = 0; nt < 2; ++nt) {
          int dim = h * 32 + nt * 16 + c0;
          bf16x8 b0 = *(const bf16x8*)(vt + (size_t)dim * PH + quad * 8);
          bf16x8 b1v = *(const bf16x8*)(vt + (size_t)dim * PH + 32 + quad * 8);
          f32x4 acc = {0.f, 0.f, 0.f, 0.f};
          acc = __builtin_amdgcn_mfma_f32_16x16x32_bf16(a0, b0, acc, 0, 0, 0);
          acc = __builtin_amdgcn_mfma_f32_16x16x32_bf16(a1, b1v, acc, 0, 0, 0);
#pragma unroll
          for (int r = 0; r < 4; ++r)
            qh[(mt * 16 + quad * 4 + r) * PH + dim] = f2b(acc[r]);
        }
      }
    }

    {
      f32x4 o4[4];
      mm64(qh, Wo, arow, quad, lane, o4);
      ln_epilogue(o4, xh, ln1g + blk * SD, ln1b + blk * SD, nullptr, mt, quad, c0);
    }

    f32x4 facc[4];
#pragma unroll
    for (int nt = 0; nt < 4; ++nt) facc[nt] = (f32x4){0.f, 0.f, 0.f, 0.f};
#pragma unroll 1
    for (int c = 0; c < 4; ++c) {
      {
        bf16x8 a0 = *(const bf16x8*)(xh + arow * PH + quad * 8);
        bf16x8 a1 = *(const bf16x8*)(xh + arow * PH + 32 + quad * 8);
#pragma unroll
        for (int nt = 0; nt < 4; ++nt) {
          int ntg = c * 4 + nt;
          f32x4 acc = {0.f, 0.f, 0.f, 0.f};
          acc = __builtin_amdgcn_mfma_f32_16x16x32_bf16(a0, ldB(W1, 0 * 16 + ntg, lane), acc, 0, 0, 0);
          acc = __builtin_amdgcn_mfma_f32_16x16x32_bf16(a1, ldB(W1, 1 * 16 + ntg, lane), acc, 0, 0, 0);
          int cc = nt * 16 + c0;
          float b1v = b1[blk * 256 + c * 64 + cc];
#pragma unroll
          for (int r = 0; r < 4; ++r)
            qh[(mt * 16 + quad * 4 + r) * PH + cc] = f2b(gelu_fast(acc[r] + b1v));
        }
      }
      {
        bf16x8 a0 = *(const bf16x8*)(qh + arow * PH + quad * 8);
        bf16x8 a1 = *(const bf16x8*)(qh + arow * PH + 32 + quad * 8);
#pragma unroll
        for (int nt = 0; nt < 4; ++nt) {
          facc[nt] = __builtin_amdgcn_mfma_f32_16x16x32_bf16(a0, ldB(W2, (2 * c) * 4 + nt, lane), facc[nt], 0, 0, 0);
          facc[nt] = __builtin_amdgcn_mfma_f32_16x16x32_bf16(a1, ldB(W2, (2 * c + 1) * 4 + nt, lane), facc[nt], 0, 0, 0);
        }
      }
    }

    ln_epilogue(facc, xh, ln2g + blk * SD, ln2b + blk * SD, b2 + blk * SD, mt, quad, c0);
  }
  __syncthreads();

  if (mt == 0) {
    int sl = len - 1;
    float val = b2f(xh[sl * PH + lane]);
    float2 ss = wred_sum2(val, val * val);
    float m = ss.x * (1.f / 64);
    float var = fmaxf(ss.y * (1.f / 64) - m * m, 0.f);
    float rs = rsqrtf(var + 1e-5f);
    out[b * SD + lane] = (val - m) * rs * lnfg[lane] + lnfb[lane];
  }
}

// ---------------------------------------------------------------------------
extern "C" void kernel_launch(void* const* d_in, const int* in_sizes, int n_in,
                              void* d_out, int out_size, void* d_ws, size_t ws_size,
                              hipStream_t stream) {
  const int*   seq   = (const int*)d_in[0];
  const int*   lens  = (const int*)d_in[1];
  const int*   ei    = (const int*)d_in[2];
  const float* ew    = (const float*)d_in[3];
  const float* bert  = (const float*)d_in[4];
  const float* gnn   = (const float*)d_in[5];
  const float* pw    = (const float*)d_in[6];
  const float* pb    = (const float*)d_in[7];
  const float* pos   = (const float*)d_in[8];
  const float* wq    = (const float*)d_in[9];
  const float* wk    = (const float*)d_in[10];
  const float* wv    = (const float*)d_in[11];
  const float* wo    = (const float*)d_in[12];
  const float* w1    = (const float*)d_in[13];
  const float* b1    = (const float*)d_in[14];
  const float* w2    = (const float*)d_in[15];
  const float* b2    = (const float*)d_in[16];
  const float* ln1g  = (const float*)d_in[17];
  const float* ln1b  = (const float*)d_in[18];
  const float* ln2g  = (const float*)d_in[19];
  const float* ln2b  = (const float*)d_in[20];
  const float* lnfg  = (const float*)d_in[21];
  const float* lnfb  = (const float*)d_in[22];
  float* out = (float*)d_out;

  const int E = in_sizes[2] / 2;          // 1,000,000
  const int B = in_sizes[0] / SS;         // 1024
  const int N = in_sizes[4] / SD;         // 100,001
  const int BS = B * SS;                  // 51,200

  const int* esrc = ei;
  const int* edst = ei + E;

  const int NCH = (N + 1023) >> 10;
  const int NF = (N + 15) & ~15;
  const int n32 = N * 32;

  // ---- workspace layout (counter stride cs chosen to fit)
  short* pwB; short* wqB; short* wkB; short* wvB; short* woB; short* w1B; short* w2B;
  unsigned* gnnh; unsigned* g1xh; unsigned* avgh;
  int* cntp; unsigned char* flags; int* bsum; int* rp; int2* ep;
  size_t need = 0;
  int cs = 16;
  auto layout = [&](int cstride) -> size_t {
    pwB = (short*)d_ws;
    wqB = pwB + 4096;
    wkB = wqB + 8192;
    wvB = wkB + 8192;
    woB = wvB + 8192;
    w1B = woB + 8192;
    w2B = w1B + 32768;
    gnnh = (unsigned*)(w2B + 32768);
    g1xh = gnnh + (size_t)N * 32;
    avgh = g1xh + (size_t)N * 32;
    cntp = (int*)(avgh + (size_t)N * 32);
    flags = (unsigned char*)(cntp + (size_t)(NCH << 10) * cstride);
    bsum = (int*)(flags + NF);
    rp = bsum + 128;
    ep = (int2*)((((size_t)(rp + N + 1)) + 15) & ~(size_t)15);
    return (size_t)((char*)(ep + E) - (char*)d_ws);
  };
  need = layout(16); cs = 16;
  if (need > ws_size) { need = layout(4); cs = 4; }
  if (need > ws_size) { need = layout(1); cs = 1; }

  // fp32 fallback tables (overlay the counter region)
  float* g1x = (float*)cntp;
  float* g2x = g1x + (size_t)N * SD;
  size_t need_fb = (size_t)((char*)(g2x + (size_t)N * SD) - (char*)d_ws);

  if (need <= ws_size && NCH <= 128) {
    const int cntn = (NCH << 10) * cs;
    prep_zero<<<1024, 256, 0, stream>>>(pw, wq, wk, wv, wo, w1, w2,
                                        pwB, wqB, wkB, wvB, woB, w1B, w2B,
                                        cntp, cntn, (int*)flags, NF / 4);
    cvt_hist<<<(n32 + 255) / 256, 256, 0, stream>>>(gnn, gnnh, n32, edst, cntp,
                                                    cs, E, seq, flags, BS);
    gnn_chunk_sums<<<NCH, 256, 0, stream>>>(cntp, cs, bsum);
    gnn_scan_bsum<<<1, 128, 0, stream>>>(bsum, NCH);
    gnn_chunk_scan<<<NCH, 256, 0, stream>>>(cntp, cs, bsum, rp, cntp, N);
    gnn_build<<<(E + 255) / 256, 256, 0, stream>>>(esrc, edst, ew, cntp, cs, ep, E);
    const int nb = (N + 3) / 4;
    gnn_gather1<<<nb, 256, 0, stream>>>(gnnh, rp, ep, g1xh, N);
    gnn_gather_avg<<<nb, 256, 0, stream>>>(g1xh, rp, ep, gnn, avgh, N, flags);
  } else if (ws_size >= need_fb) {
    prep_zero<<<1024, 256, 0, stream>>>(pw, wq, wk, wv, wo, w1, w2,
                                        pwB, wqB, wkB, wvB, woB, w1B, w2B,
                                        (int*)d_ws, 0, (int*)d_ws, 0);
    hipMemsetAsync(g1x, 0, (size_t)2 * N * SD * sizeof(float), stream);
    const long total = (long)E * 64;
    const int sblocks = (int)((total + 255) / 256);
    gnn_scatter<<<sblocks, 256, 0, stream>>>(gnn, esrc, edst, ew, g1x, E);
    gnn_scatter<<<sblocks, 256, 0, stream>>>(g1x, esrc, edst, ew, g2x, E);
    avg_from_f32<<<(n32 + 255) / 256, 256, 0, stream>>>(gnn, g1x, g2x, avgh, n32);
  }

  seq_transformer<<<B, 256, 0, stream>>>(
      seq, lens, bert, (const short*)avgh, pb, pos,
      pwB, wqB, wkB, wvB, woB, w1B, w2B,
      b1, b2, ln1g, ln1b, ln2g, ln2b, lnfg, lnfb, out);
}

// Round 6
// 377.903 us; speedup vs baseline: 3.2647x; 1.0168x over previous
//
#include <hip/hip_runtime.h>
#include <math.h>

// ---------------------------------------------------------------------------
// HybridBERT4RecGNN forward on MI355X (gfx950), round 17.
//
// R16 counters: gnn_build 85us, WRITE_SIZE 65MB (ep is only 8MB!) -> 8x
// write amplification from random 8B CSR stores partially dirtying 64B
// lines in MULTIPLE non-coherent XCD L2s.
// R17:
//  (a) dst-PARTITIONED build: 1024 blocks, partition p = bid & 7 (bid%8 ->
//      XCD round-robin heuristic); block processes only edges with dst in
//      [p*N/8,(p+1)*N/8), grid-striding the whole edge list. Each ep line
//      is then written by exactly ONE XCD and becomes fully dirty in one
//      L2 -> writeback ~8MB instead of 65MB. Cost: dst list read 8x
//      (32MB streamed). Correctness independent of the XCD mapping.
//  (b) gnn_scan_bsum fused into gnn_chunk_scan (block sums its <=98
//      predecessors' chunk totals directly): 8 -> 7 dispatches.
//  Everything else byte-identical to R16 (384us, passed).
// ---------------------------------------------------------------------------

typedef __attribute__((ext_vector_type(8))) short bf16x8;
typedef __attribute__((ext_vector_type(4))) float f32x4;

#define SD   64
#define SS   50
#define NBLK 2
#define PH   72    // LDS pitch in halves (144 B, 16B-aligned rows, 2-way banks max)

__device__ __forceinline__ short f2b(float f) {  // fp32 -> bf16 RNE (HW cvt)
  union { __bf16 h; short s; } u;
  u.h = (__bf16)f;
  return u.s;
}
__device__ __forceinline__ float b2f(short s) {
  union { unsigned u; float f; } v;
  v.u = ((unsigned)(unsigned short)s) << 16;
  return v.f;
}
__device__ __forceinline__ unsigned packb(float a, float b) {
  union { __bf16 h; unsigned short s; } ua, ub;
  ua.h = (__bf16)a; ub.h = (__bf16)b;
  return (unsigned)ua.s | ((unsigned)ub.s << 16);
}
__device__ __forceinline__ float2 wred_sum2(float a, float b) {
#pragma unroll
  for (int o = 32; o > 0; o >>= 1) {
    a += __shfl_xor(a, o, 64);
    b += __shfl_xor(b, o, 64);
  }
  return make_float2(a, b);
}
// gelu(x) = 0.5x(1+tanh(u)) = x * sigmoid(2u);  sigmoid via v_rcp_f32.
__device__ __forceinline__ float gelu_fast(float x) {
  float u = 0.7978845608028654f * x * (1.0f + 0.044715f * x * x);
  float e = __expf(-2.f * u);
  return x * __builtin_amdgcn_rcpf(1.0f + e);
}

__device__ __forceinline__ bf16x8 ldB(const short* __restrict__ Wb, int tile, int lane) {
  return *(const bf16x8*)(Wb + ((size_t)tile * 64 + lane) * 8);
}

// [own 16 rows x K=64] @ [64x64] -> D own rows. A from LDS bf16 pitch PH.
__device__ __forceinline__ void mm64(const short* A, const short* __restrict__ Wb,
                                     int arow, int quad, int lane, f32x4 o4[4]) {
  bf16x8 a0 = *(const bf16x8*)(A + arow * PH + quad * 8);
  bf16x8 a1 = *(const bf16x8*)(A + arow * PH + 32 + quad * 8);
#pragma unroll
  for (int nt = 0; nt < 4; ++nt) {
    f32x4 acc = {0.f, 0.f, 0.f, 0.f};
    acc = __builtin_amdgcn_mfma_f32_16x16x32_bf16(a0, ldB(Wb, 0 * 4 + nt, lane), acc, 0, 0, 0);
    acc = __builtin_amdgcn_mfma_f32_16x16x32_bf16(a1, ldB(Wb, 1 * 4 + nt, lane), acc, 0, 0, 0);
    o4[nt] = acc;
  }
}

// LN over 64 cols of D-layout values + residual from xh + optional bias.
__device__ __forceinline__ void ln_epilogue(f32x4 o4[4], short* xh,
                                            const float* __restrict__ g,
                                            const float* __restrict__ bta,
                                            const float* __restrict__ extrab,
                                            int mt, int quad, int c0) {
  float vals[4][4];
  float s1[4] = {0.f, 0.f, 0.f, 0.f}, s2[4] = {0.f, 0.f, 0.f, 0.f};
#pragma unroll
  for (int nt = 0; nt < 4; ++nt) {
    int c = nt * 16 + c0;
    float eb = extrab ? extrab[c] : 0.f;
#pragma unroll
    for (int r = 0; r < 4; ++r) {
      int row = mt * 16 + quad * 4 + r;
      float v = o4[nt][r] + b2f(xh[row * PH + c]) + eb;
      vals[nt][r] = v;
      s1[r] += v;
      s2[r] += v * v;
    }
  }
#pragma unroll
  for (int o = 1; o < 16; o <<= 1) {
#pragma unroll
    for (int r = 0; r < 4; ++r) {
      s1[r] += __shfl_xor(s1[r], o, 64);
      s2[r] += __shfl_xor(s2[r], o, 64);
    }
  }
  float mv[4], rv[4];
#pragma unroll
  for (int r = 0; r < 4; ++r) {
    float m = s1[r] * (1.f / 64);
    float var = fmaxf(s2[r] * (1.f / 64) - m * m, 0.f);
    mv[r] = m;
    rv[r] = rsqrtf(var + 1e-5f);
  }
#pragma unroll
  for (int nt = 0; nt < 4; ++nt) {
    int c = nt * 16 + c0;
    float gv = g[c], bv = bta[c];
#pragma unroll
    for (int r = 0; r < 4; ++r) {
      int row = mt * 16 + quad * 4 + r;
      xh[row * PH + c] = f2b((vals[nt][r] - mv[r]) * rv[r] * gv + bv);
    }
  }
}

// ---------------------------------------------------------------------------
// Weight prep body
// ---------------------------------------------------------------------------
__device__ __forceinline__ void prep_body(int tid,
    const float* __restrict__ pw, const float* __restrict__ wq,
    const float* __restrict__ wk, const float* __restrict__ wv,
    const float* __restrict__ wo, const float* __restrict__ w1,
    const float* __restrict__ w2,
    short* __restrict__ pwB, short* __restrict__ wqB,
    short* __restrict__ wkB, short* __restrict__ wvB,
    short* __restrict__ woB, short* __restrict__ w1B,
    short* __restrict__ w2B) {
  int lane = tid & 63;
  int tile = tid >> 6;
  const float* W; short* out; int K, N, base;
  if (tile < 8)        { W = pw; out = pwB; K = 64;  N = 64;  base = 0; }
  else if (tile < 24)  { W = wq; out = wqB; K = 64;  N = 64;  base = 8; }
  else if (tile < 40)  { W = wk; out = wkB; K = 64;  N = 64;  base = 24; }
  else if (tile < 56)  { W = wv; out = wvB; K = 64;  N = 64;  base = 40; }
  else if (tile < 72)  { W = wo; out = woB; K = 64;  N = 64;  base = 56; }
  else if (tile < 136) { W = w1; out = w1B; K = 64;  N = 256; base = 72; }
  else if (tile < 200) { W = w2; out = w2B; K = 256; N = 64;  base = 136; }
  else return;
  int lt = tile - base;
  int KT = K / 32, NT = N / 16;
  int nt = lt % NT; lt /= NT;
  int kt = lt % KT; lt /= KT;
  int m = lt;
  const float* Wm = W + (size_t)m * K * N;
  int kbase = kt * 32 + ((lane >> 4) * 8);
  int n = nt * 16 + (lane & 15);
  short v[8];
#pragma unroll
  for (int j = 0; j < 8; ++j) v[j] = f2b(Wm[(size_t)(kbase + j) * N + n]);
  *(bf16x8*)(out + ((size_t)(tile - base) * 64 + lane) * 8) = *(bf16x8*)v;
}

// Weight prep + zero counters/flags (replaces memset + prep_all).
__global__ void prep_zero(const float* __restrict__ pw, const float* __restrict__ wq,
                          const float* __restrict__ wk, const float* __restrict__ wv,
                          const float* __restrict__ wo, const float* __restrict__ w1,
                          const float* __restrict__ w2,
                          short* __restrict__ pwB, short* __restrict__ wqB,
                          short* __restrict__ wkB, short* __restrict__ wvB,
                          short* __restrict__ woB, short* __restrict__ w1B,
                          short* __restrict__ w2B,
                          int* __restrict__ cntp, int cntn,
                          int* __restrict__ flagsw, int nfw) {
  int tid = blockIdx.x * blockDim.x + threadIdx.x;
  int NT = gridDim.x * blockDim.x;
  prep_body(tid, pw, wq, wk, wv, wo, w1, w2, pwB, wqB, wkB, wvB, woB, w1B, w2B);
  for (int i = tid; i < cntn; i += NT) cntp[i] = 0;
  for (int i = tid; i < nfw; i += NT) flagsw[i] = 0;
}

// fp32 table -> packed bf16 pairs, fused with dst-degree histogram (padded
// counters) and seq-referenced-node flagging.
__global__ void cvt_hist(const float* __restrict__ in, unsigned* __restrict__ out,
                         int n32, const int* __restrict__ dst, int* __restrict__ cntp,
                         int cs, int E, const int* __restrict__ seq,
                         unsigned char* __restrict__ flags, int BS) {
  int i = blockIdx.x * blockDim.x + threadIdx.x;
  if (i < n32) {
    float2 f = ((const float2*)in)[i];
    out[i] = packb(f.x, f.y);
  }
  if (i < E) atomicAdd(&cntp[dst[i] * cs], 1);
  if (i < BS) flags[seq[i]] = 1;
}

// ---------------------------------------------------------------------------
// CSR scan: chunk_sums (per-chunk totals) -> chunk_scan (fused predecessor
// sum + per-chunk exclusive scan; bsum fully written at dispatch boundary).
// ---------------------------------------------------------------------------
__global__ void gnn_chunk_sums(const int* __restrict__ cntp, int cs,
                               int* __restrict__ bsum) {
  __shared__ int ssum;
  if (threadIdx.x == 0) ssum = 0;
  __syncthreads();
  int base = blockIdx.x * 1024 + threadIdx.x * 4;
  int s = cntp[base * cs] + cntp[(base + 1) * cs] + cntp[(base + 2) * cs] +
          cntp[(base + 3) * cs];
#pragma unroll
  for (int o = 32; o > 0; o >>= 1) s += __shfl_xor(s, o, 64);
  if ((threadIdx.x & 63) == 0) atomicAdd(&ssum, s);
  __syncthreads();
  if (threadIdx.x == 0) bsum[blockIdx.x] = ssum;
}

__global__ void gnn_chunk_scan(const int* __restrict__ cntp_in, int cs,
                               const int* __restrict__ bsum,
                               int* __restrict__ rp, int* __restrict__ cntp,
                               int Nn) {
  __shared__ int wsum[4];
  __shared__ int bofs_sh;
  int bx = blockIdx.x, t = threadIdx.x, lane = t & 63, wv = t >> 6;
  int base = bx * 1024 + t * 4;
  int c0 = cntp_in[base * cs], c1 = cntp_in[(base + 1) * cs];
  int c2 = cntp_in[(base + 2) * cs], c3 = cntp_in[(base + 3) * cs];
  int s = c0 + c1 + c2 + c3;
  int x = s;
#pragma unroll
  for (int o = 1; o < 64; o <<= 1) {
    int y = __shfl_up(x, o, 64);
    if (lane >= o) x += y;
  }
  if (lane == 63) wsum[wv] = x;
  // fused predecessor sum (wave 1 to overlap with wave scans elsewhere)
  if (wv == 0) {
    int ps = 0;
    for (int i = lane; i < bx; i += 64) ps += bsum[i];
#pragma unroll
    for (int o = 32; o > 0; o >>= 1) ps += __shfl_xor(ps, o, 64);
    if (lane == 0) bofs_sh = ps;
  }
  __syncthreads();
  int wo = 0;
#pragma unroll
  for (int i = 0; i < 4; ++i) if (i < wv) wo += wsum[i];
  int excl = bofs_sh + wo + (x - s);
  int p[4];
  p[0] = excl; p[1] = p[0] + c0; p[2] = p[1] + c1; p[3] = p[2] + c2;
#pragma unroll
  for (int j = 0; j < 4; ++j) {
    int idx = base + j;
    if (idx <= Nn) rp[idx] = p[j];
    if (idx < Nn) cntp[idx * cs] = p[j];   // wp aliases cnt
  }
}

// ---------------------------------------------------------------------------
// dst-partitioned CSR build. partition p = bid & 7 (bid%8 round-robins
// across the 8 XCDs); block processes only edges with dst in p's node
// range -> each ep line written by exactly one XCD -> full-line dirty in
// one L2, ~8MB writeback instead of 65MB. dst list read 8x (streamed).
// ---------------------------------------------------------------------------
__global__ void gnn_build(const int* __restrict__ src, const int* __restrict__ dst,
                          const float* __restrict__ ew, int* __restrict__ cntp,
                          int cs, int2* __restrict__ ep, int E, int Nn) {
  int p = blockIdx.x & 7;
  int sub = blockIdx.x >> 3;
  int nsub = gridDim.x >> 3;
  int lo = (int)(((long)p * Nn) >> 3);
  int hi = (int)(((long)(p + 1) * Nn) >> 3);
  for (int e = sub * 256 + threadIdx.x; e < E; e += nsub * 256) {
    int d = dst[e];
    if (d >= lo && d < hi) {
      int pos = atomicAdd(&cntp[d * cs], 1);
      ep[pos] = make_int2(src[e], __float_as_int(ew[e]));
    }
  }
}

// ---------------------------------------------------------------------------
// Gather kernels, 8-slot wave-per-node (unchanged).
// ---------------------------------------------------------------------------
__device__ __forceinline__ void gather1_node(int n, int lane,
    const unsigned* __restrict__ xinh, const int* __restrict__ rp,
    const int2* __restrict__ ep, unsigned* __restrict__ xouth) {
  int slot = lane >> 3;
  int g = lane & 7;
  int beg = rp[n], end = rp[n + 1];
  float a[8] = {0.f, 0.f, 0.f, 0.f, 0.f, 0.f, 0.f, 0.f};
  for (int e = beg + slot; e < end; e += 8) {
    int2 ee = ep[e];
    float w = __int_as_float(ee.y);
    uint4 p = *(const uint4*)(xinh + (size_t)ee.x * 32 + g * 4);
    a[0] += b2f((short)(p.x & 0xFFFF)) * w;
    a[1] += b2f((short)(p.x >> 16)) * w;
    a[2] += b2f((short)(p.y & 0xFFFF)) * w;
    a[3] += b2f((short)(p.y >> 16)) * w;
    a[4] += b2f((short)(p.z & 0xFFFF)) * w;
    a[5] += b2f((short)(p.z >> 16)) * w;
    a[6] += b2f((short)(p.w & 0xFFFF)) * w;
    a[7] += b2f((short)(p.w >> 16)) * w;
  }
#pragma unroll
  for (int o = 8; o < 64; o <<= 1)
#pragma unroll
    for (int j = 0; j < 8; ++j) a[j] += __shfl_xor(a[j], o, 64);
  if (slot == 0) {
    uint4 o4;
    o4.x = packb(a[0], a[1]);
    o4.y = packb(a[2], a[3]);
    o4.z = packb(a[4], a[5]);
    o4.w = packb(a[6], a[7]);
    *(uint4*)(xouth + (size_t)n * 32 + g * 4) = o4;
  }
}

__device__ __forceinline__ void gatheravg_node(int n, int lane,
    const unsigned* __restrict__ x1h, const int* __restrict__ rp,
    const int2* __restrict__ ep, const float* __restrict__ gnn,
    unsigned* __restrict__ avgh) {
  int slot = lane >> 3;
  int g = lane & 7;
  int beg = rp[n], end = rp[n + 1];
  float a[8] = {0.f, 0.f, 0.f, 0.f, 0.f, 0.f, 0.f, 0.f};
  for (int e = beg + slot; e < end; e += 8) {
    int2 ee = ep[e];
    float w = __int_as_float(ee.y);
    uint4 p = *(const uint4*)(x1h + (size_t)ee.x * 32 + g * 4);
    a[0] += b2f((short)(p.x & 0xFFFF)) * w;
    a[1] += b2f((short)(p.x >> 16)) * w;
    a[2] += b2f((short)(p.y & 0xFFFF)) * w;
    a[3] += b2f((short)(p.y >> 16)) * w;
    a[4] += b2f((short)(p.z & 0xFFFF)) * w;
    a[5] += b2f((short)(p.z >> 16)) * w;
    a[6] += b2f((short)(p.w & 0xFFFF)) * w;
    a[7] += b2f((short)(p.w >> 16)) * w;
  }
#pragma unroll
  for (int o = 8; o < 64; o <<= 1)
#pragma unroll
    for (int j = 0; j < 8; ++j) a[j] += __shfl_xor(a[j], o, 64);
  if (slot == 0) {
    uint4 own = *(const uint4*)(x1h + (size_t)n * 32 + g * 4);
    float4 g0 = *(const float4*)(gnn + (size_t)n * 64 + g * 8);
    float4 g1 = *(const float4*)(gnn + (size_t)n * 64 + g * 8 + 4);
    float v0 = (g0.x + b2f((short)(own.x & 0xFFFF)) + a[0]) * (1.f / 3.f);
    float v1 = (g0.y + b2f((short)(own.x >> 16)) + a[1]) * (1.f / 3.f);
    float v2 = (g0.z + b2f((short)(own.y & 0xFFFF)) + a[2]) * (1.f / 3.f);
    float v3 = (g0.w + b2f((short)(own.y >> 16)) + a[3]) * (1.f / 3.f);
    float v4 = (g1.x + b2f((short)(own.z & 0xFFFF)) + a[4]) * (1.f / 3.f);
    float v5 = (g1.y + b2f((short)(own.z >> 16)) + a[5]) * (1.f / 3.f);
    float v6 = (g1.z + b2f((short)(own.w & 0xFFFF)) + a[6]) * (1.f / 3.f);
    float v7 = (g1.w + b2f((short)(own.w >> 16)) + a[7]) * (1.f / 3.f);
    uint4 o4;
    o4.x = packb(v0, v1);
    o4.y = packb(v2, v3);
    o4.z = packb(v4, v5);
    o4.w = packb(v6, v7);
    *(uint4*)(avgh + (size_t)n * 32 + g * 4) = o4;
  }
}

__global__ void gnn_gather1(const unsigned* __restrict__ xinh,
                            const int* __restrict__ rp, const int2* __restrict__ ep,
                            unsigned* __restrict__ xouth, int Nn) {
  int n = blockIdx.x * 4 + (threadIdx.x >> 6);
  if (n >= Nn) return;
  gather1_node(n, threadIdx.x & 63, xinh, rp, ep, xouth);
}

__global__ void gnn_gather_avg(const unsigned* __restrict__ x1h,
                               const int* __restrict__ rp, const int2* __restrict__ ep,
                               const float* __restrict__ gnn,
                               unsigned* __restrict__ avgh, int Nn,
                               const unsigned char* __restrict__ flags) {
  int n = blockIdx.x * 4 + (threadIdx.x >> 6);
  if (n >= Nn) return;
  if (!flags[n]) return;
  gatheravg_node(n, threadIdx.x & 63, x1h, rp, ep, gnn, avgh);
}

// fp32 scatter fallback helpers
__global__ void gnn_scatter(const float* __restrict__ xin,
                            const int* __restrict__ src,
                            const int* __restrict__ dst,
                            const float* __restrict__ ew,
                            float* __restrict__ xout, int E) {
  int gid = blockIdx.x * blockDim.x + threadIdx.x;
  int e = gid >> 6;
  int d = gid & 63;
  if (e >= E) return;
  atomicAdd(&xout[(size_t)dst[e] * SD + d], xin[(size_t)src[e] * SD + d] * ew[e]);
}
__global__ void avg_from_f32(const float* __restrict__ gnn, const float* __restrict__ g1,
                             const float* __restrict__ g2, unsigned* __restrict__ avgh,
                             int n32) {
  int i = blockIdx.x * blockDim.x + threadIdx.x;
  if (i >= n32) return;
  float2 a = ((const float2*)gnn)[i];
  float2 b = ((const float2*)g1)[i];
  float2 c = ((const float2*)g2)[i];
  avgh[i] = packb((a.x + b.x + c.x) * (1.f / 3.f), (a.y + b.y + c.y) * (1.f / 3.f));
}

// ---------------------------------------------------------------------------
// MFMA transformer, row-ownership version (byte-identical to R12/R13/R16).
// ---------------------------------------------------------------------------
__global__ __launch_bounds__(256, 3)
void seq_transformer(const int* __restrict__ seq, const int* __restrict__ lengths,
                     const float* __restrict__ bert, const short* __restrict__ avgh,
                     const float* __restrict__ pbias, const float* __restrict__ pos,
                     const short* __restrict__ pwB, const short* __restrict__ wqB,
                     const short* __restrict__ wkB, const short* __restrict__ wvB,
                     const short* __restrict__ woB, const short* __restrict__ w1B,
                     const short* __restrict__ w2B,
                     const float* __restrict__ b1, const float* __restrict__ b2,
                     const float* __restrict__ ln1g, const float* __restrict__ ln1b,
                     const float* __restrict__ ln2g, const float* __restrict__ ln2b,
                     const float* __restrict__ lnfg, const float* __restrict__ lnfb,
                     float* __restrict__ out) {
  __shared__ short xh[64 * PH];
  __shared__ short qh[64 * PH];
  __shared__ short kh[64 * PH];
  __shared__ short vt[64 * PH];
  __shared__ short s0[64 * PH];
  __shared__ int   sidx[64];

  const int t = threadIdx.x;
  const int lane = t & 63;
  const int mt = t >> 6;
  const int quad = lane >> 4;
  const int c0 = lane & 15;
  const int b = blockIdx.x;
  const int arow = mt * 16 + c0;

  if (t < 64) sidx[t] = (t < SS) ? seq[b * SS + t] : 0;
  __syncthreads();

  const int len = lengths[b];
  const float alpha = (len <= 10) ? 0.3f : ((len >= 50) ? 0.7f : 0.5f);
  const float isq = 0.17677669529663687f;

  float kbias[4];
#pragma unroll
  for (int nt = 0; nt < 4; ++nt) {
    int key = nt * 16 + c0;
    kbias[nt] = (key < SS && sidx[key] != 0) ? 0.f : -1e9f;
  }

#pragma unroll
  for (int ir = 0; ir < 16; ++ir) {
    int s = mt * 16 + ir;
    short v = 0;
    if (s < SS) v = avgh[(size_t)sidx[s] * SD + lane];
    qh[s * PH + lane] = v;
  }

  {
    f32x4 o4[4];
    mm64(qh, pwB, arow, quad, lane, o4);
#pragma unroll
    for (int nt = 0; nt < 4; ++nt) {
      int c = nt * 16 + c0;
      float pbv = pbias[c];
#pragma unroll
      for (int r = 0; r < 4; ++r) {
        int row = mt * 16 + quad * 4 + r;
        short ov = 0;
        if (row < SS) {
          float g = o4[nt][r] + pbv;
          float xv = alpha * bert[(size_t)sidx[row] * SD + c] +
                     (1.f - alpha) * g + pos[row * SD + c];
          ov = f2b(xv);
        }
        xh[row * PH + c] = ov;
      }
    }
  }

#pragma unroll 1
  for (int blk = 0; blk < NBLK; ++blk) {
    const short* Wq = wqB + blk * 4096;
    const short* Wk = wkB + blk * 4096;
    const short* Wv = wvB + blk * 4096;
    const short* Wo = woB + blk * 4096;
    const short* W1 = w1B + blk * 16384;
    const short* W2 = w2B + blk * 16384;

    __syncthreads();

    {
      f32x4 o4[4];
      mm64(xh, Wq, arow, quad, lane, o4);
#pragma unroll
      for (int nt = 0; nt < 4; ++nt) {
        int c = nt * 16 + c0;
#pragma unroll
        for (int r = 0; r < 4; ++r) qh[(mt * 16 + quad * 4 + r) * PH + c] = f2b(o4[nt][r]);
      }
      mm64(xh, Wk, arow, quad, lane, o4);
#pragma unroll
      for (int nt = 0; nt < 4; ++nt) {
        int c = nt * 16 + c0;
#pragma unroll
        for (int r = 0; r < 4; ++r) kh[(mt * 16 + quad * 4 + r) * PH + c] = f2b(o4[nt][r]);
      }
      mm64(xh, Wv, arow, quad, lane, o4);
#pragma unroll
      for (int nt = 0; nt < 4; ++nt) {
        int dim = nt * 16 + c0;
        unsigned p0 = packb(o4[nt][0], o4[nt][1]);
        unsigned p1 = packb(o4[nt][2], o4[nt][3]);
        *(uint2*)(vt + (size_t)dim * PH + mt * 16 + quad * 4) = make_uint2(p0, p1);
      }
    }
    __syncthreads();

#pragma unroll
    for (int h = 0; h < 2; ++h) {
      {
        bf16x8 aq = *(const bf16x8*)(qh + arow * PH + h * 32 + quad * 8);
        float p[4][4];
        float mx[4], sm[4];
#pragma unroll
        for (int nt = 0; nt < 4; ++nt) {
          int key = nt * 16 + c0;
          bf16x8 bk = *(const bf16x8*)(kh + key * PH + h * 32 + quad * 8);
          f32x4 acc = {0.f, 0.f, 0.f, 0.f};
          acc = __builtin_amdgcn_mfma_f32_16x16x32_bf16(aq, bk, acc, 0, 0, 0);
#pragma unroll
          for (int r = 0; r < 4; ++r) p[nt][r] = fmaf(acc[r], isq, kbias[nt]);
        }
#pragma unroll
        for (int r = 0; r < 4; ++r)
          mx[r] = fmaxf(fmaxf(p[0][r], p[1][r]), fmaxf(p[2][r], p[3][r]));
#pragma unroll
        for (int o = 1; o < 16; o <<= 1)
#pragma unroll
          for (int r = 0; r < 4; ++r) mx[r] = fmaxf(mx[r], __shfl_xor(mx[r], o, 64));
#pragma unroll
        for (int r = 0; r < 4; ++r) sm[r] = 0.f;
#pragma unroll
        for (int nt = 0; nt < 4; ++nt)
#pragma unroll
          for (int r = 0; r < 4; ++r) {
            float e = __expf(p[nt][r] - mx[r]);
            p[nt][r] = e;
            sm[r] += e;
          }
#pragma unroll
        for (int o = 1; o < 16; o <<= 1)
#pragma unroll
          for (int r = 0; r < 4; ++r) sm[r] += __shfl_xor(sm[r], o, 64);
#pragma unroll
        for (int r = 0; r < 4; ++r) {
          float inv = __builtin_amdgcn_rcpf(sm[r]);
          int q = mt * 16 + quad * 4 + r;
#pragma unroll
          for (int nt = 0; nt < 4; ++nt)
            s0[q * PH + nt * 16 + c0] = f2b(p[nt][r] * inv);
        }
      }
      {
        bf16x8 a0 = *(const bf16x8*)(s0 + arow * PH + quad * 8);
        bf16x8 a1 = *(const bf16x8*)(s0 + arow * PH + 32 + quad * 8);
#pragma unroll
        for (int nt = 0; nt < 2; ++nt) {
          int dim = h * 32 + nt * 16 + c0;
          bf16x8 b0 = *(const bf16x8*)(vt + (size_t)dim * PH + quad * 8);
          bf16x8 b1v = *(const bf16x8*)(vt + (size_t)dim * PH + 32 + quad * 8);
          f32x4 acc = {0.f, 0.f, 0.f, 0.f};
          acc = __builtin_amdgcn_mfma_f32_16x16x32_bf16(a0, b0, acc, 0, 0, 0);
          acc = __builtin_amdgcn_mfma_f32_16x16x32_bf16(a1, b1v, acc, 0, 0, 0);
#pragma unroll
          for (int r = 0; r < 4; ++r)
            qh[(mt * 16 + quad * 4 + r) * PH + dim] = f2b(acc[r]);
        }
      }
    }

    {
      f32x4 o4[4];
      mm64(qh, Wo, arow, quad, lane, o4);
      ln_epilogue(o4, xh, ln1g + blk * SD, ln1b + blk * SD, nullptr, mt, quad, c0);
    }

    f32x4 facc[4];
#pragma unroll
    for (int nt = 0; nt < 4; ++nt) facc[nt] = (f32x4){0.f, 0.f, 0.f, 0.f};
#pragma unroll 1
    for (int c = 0; c < 4; ++c) {
      {
        bf16x8 a0 = *(const bf16x8*)(xh + arow * PH + quad * 8);
        bf16x8 a1 = *(const bf16x8*)(xh + arow * PH + 32 + quad * 8);
#pragma unroll
        for (int nt = 0; nt < 4; ++nt) {
          int ntg = c * 4 + nt;
          f32x4 acc = {0.f, 0.f, 0.f, 0.f};
          acc = __builtin_amdgcn_mfma_f32_16x16x32_bf16(a0, ldB(W1, 0 * 16 + ntg, lane), acc, 0, 0, 0);
          acc = __builtin_amdgcn_mfma_f32_16x16x32_bf16(a1, ldB(W1, 1 * 16 + ntg, lane), acc, 0, 0, 0);
          int cc = nt * 16 + c0;
          float b1v = b1[blk * 256 + c * 64 + cc];
#pragma unroll
          for (int r = 0; r < 4; ++r)
            qh[(mt * 16 + quad * 4 + r) * PH + cc] = f2b(gelu_fast(acc[r] + b1v));
        }
      }
      {
        bf16x8 a0 = *(const bf16x8*)(qh + arow * PH + quad * 8);
        bf16x8 a1 = *(const bf16x8*)(qh + arow * PH + 32 + quad * 8);
#pragma unroll
        for (int nt = 0; nt < 4; ++nt) {
          facc[nt] = __builtin_amdgcn_mfma_f32_16x16x32_bf16(a0, ldB(W2, (2 * c) * 4 + nt, lane), facc[nt], 0, 0, 0);
          facc[nt] = __builtin_amdgcn_mfma_f32_16x16x32_bf16(a1, ldB(W2, (2 * c + 1) * 4 + nt, lane), facc[nt], 0, 0, 0);
        }
      }
    }

    ln_epilogue(facc, xh, ln2g + blk * SD, ln2b + blk * SD, b2 + blk * SD, mt, quad, c0);
  }
  __syncthreads();

  if (mt == 0) {
    int sl = len - 1;
    float val = b2f(xh[sl * PH + lane]);
    float2 ss = wred_sum2(val, val * val);
    float m = ss.x * (1.f / 64);
    float var = fmaxf(ss.y * (1.f / 64) - m * m, 0.f);
    float rs = rsqrtf(var + 1e-5f);
    out[b * SD + lane] = (val - m) * rs * lnfg[lane] + lnfb[lane];
  }
}

// ---------------------------------------------------------------------------
extern "C" void kernel_launch(void* const* d_in, const int* in_sizes, int n_in,
                              void* d_out, int out_size, void* d_ws, size_t ws_size,
                              hipStream_t stream) {
  const int*   seq   = (const int*)d_in[0];
  const int*   lens  = (const int*)d_in[1];
  const int*   ei    = (const int*)d_in[2];
  const float* ew    = (const float*)d_in[3];
  const float* bert  = (const float*)d_in[4];
  const float* gnn   = (const float*)d_in[5];
  const float* pw    = (const float*)d_in[6];
  const float* pb    = (const float*)d_in[7];
  const float* pos   = (const float*)d_in[8];
  const float* wq    = (const float*)d_in[9];
  const float* wk    = (const float*)d_in[10];
  const float* wv    = (const float*)d_in[11];
  const float* wo    = (const float*)d_in[12];
  const float* w1    = (const float*)d_in[13];
  const float* b1    = (const float*)d_in[14];
  const float* w2    = (const float*)d_in[15];
  const float* b2    = (const float*)d_in[16];
  const float* ln1g  = (const float*)d_in[17];
  const float* ln1b  = (const float*)d_in[18];
  const float* ln2g  = (const float*)d_in[19];
  const float* ln2b  = (const float*)d_in[20];
  const float* lnfg  = (const float*)d_in[21];
  const float* lnfb  = (const float*)d_in[22];
  float* out = (float*)d_out;

  const int E = in_sizes[2] / 2;          // 1,000,000
  const int B = in_sizes[0] / SS;         // 1024
  const int N = in_sizes[4] / SD;         // 100,001
  const int BS = B * SS;                  // 51,200

  const int* esrc = ei;
  const int* edst = ei + E;

  const int NCH = (N + 1023) >> 10;
  const int NF = (N + 15) & ~15;
  const int n32 = N * 32;

  // ---- workspace layout (counter stride cs chosen to fit)
  short* pwB; short* wqB; short* wkB; short* wvB; short* woB; short* w1B; short* w2B;
  unsigned* gnnh; unsigned* g1xh; unsigned* avgh;
  int* cntp; unsigned char* flags; int* bsum; int* rp; int2* ep;
  size_t need = 0;
  int cs = 16;
  auto layout = [&](int cstride) -> size_t {
    pwB = (short*)d_ws;
    wqB = pwB + 4096;
    wkB = wqB + 8192;
    wvB = wkB + 8192;
    woB = wvB + 8192;
    w1B = woB + 8192;
    w2B = w1B + 32768;
    gnnh = (unsigned*)(w2B + 32768);
    g1xh = gnnh + (size_t)N * 32;
    avgh = g1xh + (size_t)N * 32;
    cntp = (int*)(avgh + (size_t)N * 32);
    flags = (unsigned char*)(cntp + (size_t)(NCH << 10) * cstride);
    bsum = (int*)(flags + NF);
    rp = bsum + 128;
    ep = (int2*)((((size_t)(rp + N + 1)) + 15) & ~(size_t)15);
    return (size_t)((char*)(ep + E) - (char*)d_ws);
  };
  need = layout(16); cs = 16;
  if (need > ws_size) { need = layout(4); cs = 4; }
  if (need > ws_size) { need = layout(1); cs = 1; }

  // fp32 fallback tables (overlay the counter region)
  float* g1x = (float*)cntp;
  float* g2x = g1x + (size_t)N * SD;
  size_t need_fb = (size_t)((char*)(g2x + (size_t)N * SD) - (char*)d_ws);

  if (need <= ws_size && NCH <= 128) {
    const int cntn = (NCH << 10) * cs;
    prep_zero<<<1024, 256, 0, stream>>>(pw, wq, wk, wv, wo, w1, w2,
                                        pwB, wqB, wkB, wvB, woB, w1B, w2B,
                                        cntp, cntn, (int*)flags, NF / 4);
    cvt_hist<<<(n32 + 255) / 256, 256, 0, stream>>>(gnn, gnnh, n32, edst, cntp,
                                                    cs, E, seq, flags, BS);
    gnn_chunk_sums<<<NCH, 256, 0, stream>>>(cntp, cs, bsum);
    gnn_chunk_scan<<<NCH, 256, 0, stream>>>(cntp, cs, bsum, rp, cntp, N);
    gnn_build<<<1024, 256, 0, stream>>>(esrc, edst, ew, cntp, cs, ep, E, N);
    const int nb = (N + 3) / 4;
    gnn_gather1<<<nb, 256, 0, stream>>>(gnnh, rp, ep, g1xh, N);
    gnn_gather_avg<<<nb, 256, 0, stream>>>(g1xh, rp, ep, gnn, avgh, N, flags);
  } else if (ws_size >= need_fb) {
    prep_zero<<<1024, 256, 0, stream>>>(pw, wq, wk, wv, wo, w1, w2,
                                        pwB, wqB, wkB, wvB, woB, w1B, w2B,
                                        (int*)d_ws, 0, (int*)d_ws, 0);
    hipMemsetAsync(g1x, 0, (size_t)2 * N * SD * sizeof(float), stream);
    const long total = (long)E * 64;
    const int sblocks = (int)((total + 255) / 256);
    gnn_scatter<<<sblocks, 256, 0, stream>>>(gnn, esrc, edst, ew, g1x, E);
    gnn_scatter<<<sblocks, 256, 0, stream>>>(g1x, esrc, edst, ew, g2x, E);
    avg_from_f32<<<(n32 + 255) / 256, 256, 0, stream>>>(gnn, g1x, g2x, avgh, n32);
  }

  seq_transformer<<<B, 256, 0, stream>>>(
      seq, lens, bert, (const short*)avgh, pb, pos,
      pwB, wqB, wkB, wvB, woB, w1B, w2B,
      b1, b2, ln1g, ln1b, ln2g, ln2b, lnfg, lnfb, out);
}

// Round 7
// 341.498 us; speedup vs baseline: 3.6128x; 1.1066x over previous
//
#include <hip/hip_runtime.h>
#include <math.h>

// ---------------------------------------------------------------------------
// HybridBERT4RecGNN forward on MI355X (gfx950), round 18.
//
// R17: wall 378us, transformer 82us -> ~296us across 7 sub-82us GNN
// dispatches (hist ~50, build ~60-80, scans ~20, gathers ~100, prep ~20).
// R18: SLOT-DIRECT CSR -- degrees are Poisson(10), so a fixed-capacity
// layout ep[n*CAP+pos] (CAP=32, P(deg>32)~2e-9) makes the first atomic
// pass itself the build: histogram + 2 scan kernels deleted. Correctness
// kept via an overflow list (atomic append; gathers scan it only for
// nodes with deg>CAP, expected zero entries for this input).
//  - bf16 convert moved into prep_zero (no dependence on counters).
//  - avgh ALIASES gnnh (dead after gather1) -> slot table fits workspace.
//  - build keeps R17 dst-partitioning (bid&7 -> XCD) for single-L2 lines.
// Pipeline: prep_zero_cvt, build_fixed, gather1, gather_avg, transformer
// = 5 dispatches (was 8). Transformer byte-identical (82us proven).
// ---------------------------------------------------------------------------

typedef __attribute__((ext_vector_type(8))) short bf16x8;
typedef __attribute__((ext_vector_type(4))) float f32x4;

#define SD   64
#define SS   50
#define NBLK 2
#define PH   72    // LDS pitch in halves (144 B, 16B-aligned rows, 2-way banks max)
#define OVCAP 8192

__device__ __forceinline__ short f2b(float f) {  // fp32 -> bf16 RNE (HW cvt)
  union { __bf16 h; short s; } u;
  u.h = (__bf16)f;
  return u.s;
}
__device__ __forceinline__ float b2f(short s) {
  union { unsigned u; float f; } v;
  v.u = ((unsigned)(unsigned short)s) << 16;
  return v.f;
}
__device__ __forceinline__ unsigned packb(float a, float b) {
  union { __bf16 h; unsigned short s; } ua, ub;
  ua.h = (__bf16)a; ub.h = (__bf16)b;
  return (unsigned)ua.s | ((unsigned)ub.s << 16);
}
__device__ __forceinline__ float2 wred_sum2(float a, float b) {
#pragma unroll
  for (int o = 32; o > 0; o >>= 1) {
    a += __shfl_xor(a, o, 64);
    b += __shfl_xor(b, o, 64);
  }
  return make_float2(a, b);
}
// gelu(x) = 0.5x(1+tanh(u)) = x * sigmoid(2u);  sigmoid via v_rcp_f32.
__device__ __forceinline__ float gelu_fast(float x) {
  float u = 0.7978845608028654f * x * (1.0f + 0.044715f * x * x);
  float e = __expf(-2.f * u);
  return x * __builtin_amdgcn_rcpf(1.0f + e);
}

__device__ __forceinline__ bf16x8 ldB(const short* __restrict__ Wb, int tile, int lane) {
  return *(const bf16x8*)(Wb + ((size_t)tile * 64 + lane) * 8);
}

// [own 16 rows x K=64] @ [64x64] -> D own rows. A from LDS bf16 pitch PH.
__device__ __forceinline__ void mm64(const short* A, const short* __restrict__ Wb,
                                     int arow, int quad, int lane, f32x4 o4[4]) {
  bf16x8 a0 = *(const bf16x8*)(A + arow * PH + quad * 8);
  bf16x8 a1 = *(const bf16x8*)(A + arow * PH + 32 + quad * 8);
#pragma unroll
  for (int nt = 0; nt < 4; ++nt) {
    f32x4 acc = {0.f, 0.f, 0.f, 0.f};
    acc = __builtin_amdgcn_mfma_f32_16x16x32_bf16(a0, ldB(Wb, 0 * 4 + nt, lane), acc, 0, 0, 0);
    acc = __builtin_amdgcn_mfma_f32_16x16x32_bf16(a1, ldB(Wb, 1 * 4 + nt, lane), acc, 0, 0, 0);
    o4[nt] = acc;
  }
}

// LN over 64 cols of D-layout values + residual from xh + optional bias.
__device__ __forceinline__ void ln_epilogue(f32x4 o4[4], short* xh,
                                            const float* __restrict__ g,
                                            const float* __restrict__ bta,
                                            const float* __restrict__ extrab,
                                            int mt, int quad, int c0) {
  float vals[4][4];
  float s1[4] = {0.f, 0.f, 0.f, 0.f}, s2[4] = {0.f, 0.f, 0.f, 0.f};
#pragma unroll
  for (int nt = 0; nt < 4; ++nt) {
    int c = nt * 16 + c0;
    float eb = extrab ? extrab[c] : 0.f;
#pragma unroll
    for (int r = 0; r < 4; ++r) {
      int row = mt * 16 + quad * 4 + r;
      float v = o4[nt][r] + b2f(xh[row * PH + c]) + eb;
      vals[nt][r] = v;
      s1[r] += v;
      s2[r] += v * v;
    }
  }
#pragma unroll
  for (int o = 1; o < 16; o <<= 1) {
#pragma unroll
    for (int r = 0; r < 4; ++r) {
      s1[r] += __shfl_xor(s1[r], o, 64);
      s2[r] += __shfl_xor(s2[r], o, 64);
    }
  }
  float mv[4], rv[4];
#pragma unroll
  for (int r = 0; r < 4; ++r) {
    float m = s1[r] * (1.f / 64);
    float var = fmaxf(s2[r] * (1.f / 64) - m * m, 0.f);
    mv[r] = m;
    rv[r] = rsqrtf(var + 1e-5f);
  }
#pragma unroll
  for (int nt = 0; nt < 4; ++nt) {
    int c = nt * 16 + c0;
    float gv = g[c], bv = bta[c];
#pragma unroll
    for (int r = 0; r < 4; ++r) {
      int row = mt * 16 + quad * 4 + r;
      xh[row * PH + c] = f2b((vals[nt][r] - mv[r]) * rv[r] * gv + bv);
    }
  }
}

// ---------------------------------------------------------------------------
// Weight prep body
// ---------------------------------------------------------------------------
__device__ __forceinline__ void prep_body(int tid,
    const float* __restrict__ pw, const float* __restrict__ wq,
    const float* __restrict__ wk, const float* __restrict__ wv,
    const float* __restrict__ wo, const float* __restrict__ w1,
    const float* __restrict__ w2,
    short* __restrict__ pwB, short* __restrict__ wqB,
    short* __restrict__ wkB, short* __restrict__ wvB,
    short* __restrict__ woB, short* __restrict__ w1B,
    short* __restrict__ w2B) {
  int lane = tid & 63;
  int tile = tid >> 6;
  const float* W; short* out; int K, N, base;
  if (tile < 8)        { W = pw; out = pwB; K = 64;  N = 64;  base = 0; }
  else if (tile < 24)  { W = wq; out = wqB; K = 64;  N = 64;  base = 8; }
  else if (tile < 40)  { W = wk; out = wkB; K = 64;  N = 64;  base = 24; }
  else if (tile < 56)  { W = wv; out = wvB; K = 64;  N = 64;  base = 40; }
  else if (tile < 72)  { W = wo; out = woB; K = 64;  N = 64;  base = 56; }
  else if (tile < 136) { W = w1; out = w1B; K = 64;  N = 256; base = 72; }
  else if (tile < 200) { W = w2; out = w2B; K = 256; N = 64;  base = 136; }
  else return;
  int lt = tile - base;
  int KT = K / 32, NT = N / 16;
  int nt = lt % NT; lt /= NT;
  int kt = lt % KT; lt /= KT;
  int m = lt;
  const float* Wm = W + (size_t)m * K * N;
  int kbase = kt * 32 + ((lane >> 4) * 8);
  int n = nt * 16 + (lane & 15);
  short v[8];
#pragma unroll
  for (int j = 0; j < 8; ++j) v[j] = f2b(Wm[(size_t)(kbase + j) * N + n]);
  *(bf16x8*)(out + ((size_t)(tile - base) * 64 + lane) * 8) = *(bf16x8*)v;
}

// Weight prep + zero counters/flags/ovcnt + fp32->bf16 table convert.
__global__ void prep_zero(const float* __restrict__ pw, const float* __restrict__ wq,
                          const float* __restrict__ wk, const float* __restrict__ wv,
                          const float* __restrict__ wo, const float* __restrict__ w1,
                          const float* __restrict__ w2,
                          short* __restrict__ pwB, short* __restrict__ wqB,
                          short* __restrict__ wkB, short* __restrict__ wvB,
                          short* __restrict__ woB, short* __restrict__ w1B,
                          short* __restrict__ w2B,
                          const float* __restrict__ gnn, unsigned* __restrict__ gnnh,
                          int n32, int* __restrict__ cntp, int cntn,
                          int* __restrict__ flagsw, int nfw, int* __restrict__ ovcnt) {
  int tid = blockIdx.x * blockDim.x + threadIdx.x;
  int NT = gridDim.x * blockDim.x;
  prep_body(tid, pw, wq, wk, wv, wo, w1, w2, pwB, wqB, wkB, wvB, woB, w1B, w2B);
  for (int i = tid; i < cntn; i += NT) cntp[i] = 0;
  for (int i = tid; i < nfw; i += NT) flagsw[i] = 0;
  if (tid < 4) ovcnt[tid] = 0;
  for (int i = tid; i < n32; i += NT) {
    float2 f = ((const float2*)gnn)[i];
    gnnh[i] = packb(f.x, f.y);
  }
}

// ---------------------------------------------------------------------------
// Slot-direct CSR build (hist+scan+build in ONE pass): pos = atomicAdd(cnt),
// ep[d*cap+pos] = edge; overflow (deg>cap, expected ZERO for Poisson(10))
// appends to ov list. dst-partitioned (bid&7 -> XCD) so each slot line is
// dirtied by a single L2. Also sets seq-referenced flags.
// ---------------------------------------------------------------------------
__global__ void gnn_build(const int* __restrict__ src, const int* __restrict__ dst,
                          const float* __restrict__ ew, int* __restrict__ cntp,
                          int cs, int cap, int2* __restrict__ ep,
                          int4* __restrict__ ov, int* __restrict__ ovcnt,
                          const int* __restrict__ seq,
                          unsigned char* __restrict__ flags, int BS,
                          int E, int Nn) {
  int tid = blockIdx.x * 256 + threadIdx.x;
  for (int i = tid; i < BS; i += gridDim.x * 256) flags[seq[i]] = 1;
  int p = blockIdx.x & 7;
  int sub = blockIdx.x >> 3;
  int nsub = gridDim.x >> 3;
  int lo = (int)(((long)p * Nn) >> 3);
  int hi = (int)(((long)(p + 1) * Nn) >> 3);
  for (int e = sub * 256 + threadIdx.x; e < E; e += nsub * 256) {
    int d = dst[e];
    if (d >= lo && d < hi) {
      int pos = atomicAdd(&cntp[d * cs], 1);
      if (pos < cap) {
        ep[(size_t)d * cap + pos] = make_int2(src[e], __float_as_int(ew[e]));
      } else {
        int oi = atomicAdd(ovcnt, 1);
        if (oi < OVCAP) ov[oi] = make_int4(d, src[e], __float_as_int(ew[e]), 0);
      }
    }
  }
}

// ---------------------------------------------------------------------------
// Gather bodies: 8 edge-slots x 8 dim-lanes; fixed-stride slot table (no
// dependent rp load); overflow list scanned only when deg > cap.
// ---------------------------------------------------------------------------
__device__ __forceinline__ void gather_accum(float a[8], const unsigned* __restrict__ tab,
                                             int srcn, float w, int g) {
  uint4 p = *(const uint4*)(tab + (size_t)srcn * 32 + g * 4);
  a[0] += b2f((short)(p.x & 0xFFFF)) * w;
  a[1] += b2f((short)(p.x >> 16)) * w;
  a[2] += b2f((short)(p.y & 0xFFFF)) * w;
  a[3] += b2f((short)(p.y >> 16)) * w;
  a[4] += b2f((short)(p.z & 0xFFFF)) * w;
  a[5] += b2f((short)(p.z >> 16)) * w;
  a[6] += b2f((short)(p.w & 0xFFFF)) * w;
  a[7] += b2f((short)(p.w >> 16)) * w;
}

__device__ __forceinline__ void gather_core(float a[8], int n, int slot, int g,
    const unsigned* __restrict__ tab, const int* __restrict__ cntp, int cs, int cap,
    const int2* __restrict__ ep, const int4* __restrict__ ov,
    const int* __restrict__ ovcnt) {
  int deg = cntp[n * cs];
  int end = min(deg, cap);
  for (int i = slot; i < end; i += 8) {
    int2 ee = ep[(size_t)n * cap + i];
    gather_accum(a, tab, ee.x, __int_as_float(ee.y), g);
  }
  if (deg > cap && slot == 0) {   // rare path: scan overflow list once
    int ovn = min(*ovcnt, OVCAP);
    for (int i = 0; i < ovn; ++i) {
      int4 e = ov[i];
      if (e.x == n) gather_accum(a, tab, e.y, __int_as_float(e.z), g);
    }
  }
}

__global__ void gnn_gather1(const unsigned* __restrict__ xinh,
                            const int* __restrict__ cntp, int cs, int cap,
                            const int2* __restrict__ ep, const int4* __restrict__ ov,
                            const int* __restrict__ ovcnt,
                            unsigned* __restrict__ xouth, int Nn) {
  int n = blockIdx.x * 4 + (threadIdx.x >> 6);
  if (n >= Nn) return;
  int lane = threadIdx.x & 63;
  int slot = lane >> 3, g = lane & 7;
  float a[8] = {0.f, 0.f, 0.f, 0.f, 0.f, 0.f, 0.f, 0.f};
  gather_core(a, n, slot, g, xinh, cntp, cs, cap, ep, ov, ovcnt);
#pragma unroll
  for (int o = 8; o < 64; o <<= 1)
#pragma unroll
    for (int j = 0; j < 8; ++j) a[j] += __shfl_xor(a[j], o, 64);
  if (slot == 0) {
    uint4 o4;
    o4.x = packb(a[0], a[1]);
    o4.y = packb(a[2], a[3]);
    o4.z = packb(a[4], a[5]);
    o4.w = packb(a[6], a[7]);
    *(uint4*)(xouth + (size_t)n * 32 + g * 4) = o4;
  }
}

__global__ void gnn_gather_avg(const unsigned* __restrict__ x1h,
                               const int* __restrict__ cntp, int cs, int cap,
                               const int2* __restrict__ ep, const int4* __restrict__ ov,
                               const int* __restrict__ ovcnt,
                               const float* __restrict__ gnn,
                               unsigned* __restrict__ avgh, int Nn,
                               const unsigned char* __restrict__ flags) {
  int n = blockIdx.x * 4 + (threadIdx.x >> 6);
  if (n >= Nn) return;
  if (!flags[n]) return;   // avgh[n] never read by transformer
  int lane = threadIdx.x & 63;
  int slot = lane >> 3, g = lane & 7;
  float a[8] = {0.f, 0.f, 0.f, 0.f, 0.f, 0.f, 0.f, 0.f};
  gather_core(a, n, slot, g, x1h, cntp, cs, cap, ep, ov, ovcnt);
#pragma unroll
  for (int o = 8; o < 64; o <<= 1)
#pragma unroll
    for (int j = 0; j < 8; ++j) a[j] += __shfl_xor(a[j], o, 64);
  if (slot == 0) {
    uint4 own = *(const uint4*)(x1h + (size_t)n * 32 + g * 4);
    float4 g0 = *(const float4*)(gnn + (size_t)n * 64 + g * 8);
    float4 g1 = *(const float4*)(gnn + (size_t)n * 64 + g * 8 + 4);
    float v0 = (g0.x + b2f((short)(own.x & 0xFFFF)) + a[0]) * (1.f / 3.f);
    float v1 = (g0.y + b2f((short)(own.x >> 16)) + a[1]) * (1.f / 3.f);
    float v2 = (g0.z + b2f((short)(own.y & 0xFFFF)) + a[2]) * (1.f / 3.f);
    float v3 = (g0.w + b2f((short)(own.y >> 16)) + a[3]) * (1.f / 3.f);
    float v4 = (g1.x + b2f((short)(own.z & 0xFFFF)) + a[4]) * (1.f / 3.f);
    float v5 = (g1.y + b2f((short)(own.z >> 16)) + a[5]) * (1.f / 3.f);
    float v6 = (g1.z + b2f((short)(own.w & 0xFFFF)) + a[6]) * (1.f / 3.f);
    float v7 = (g1.w + b2f((short)(own.w >> 16)) + a[7]) * (1.f / 3.f);
    uint4 o4;
    o4.x = packb(v0, v1);
    o4.y = packb(v2, v3);
    o4.z = packb(v4, v5);
    o4.w = packb(v6, v7);
    *(uint4*)(avgh + (size_t)n * 32 + g * 4) = o4;
  }
}

// fp32 scatter fallback helpers
__global__ void gnn_scatter(const float* __restrict__ xin,
                            const int* __restrict__ src,
                            const int* __restrict__ dst,
                            const float* __restrict__ ew,
                            float* __restrict__ xout, int E) {
  int gid = blockIdx.x * blockDim.x + threadIdx.x;
  int e = gid >> 6;
  int d = gid & 63;
  if (e >= E) return;
  atomicAdd(&xout[(size_t)dst[e] * SD + d], xin[(size_t)src[e] * SD + d] * ew[e]);
}
__global__ void avg_from_f32(const float* __restrict__ gnn, const float* __restrict__ g1,
                             const float* __restrict__ g2, unsigned* __restrict__ avgh,
                             int n32) {
  int i = blockIdx.x * blockDim.x + threadIdx.x;
  if (i >= n32) return;
  float2 a = ((const float2*)gnn)[i];
  float2 b = ((const float2*)g1)[i];
  float2 c = ((const float2*)g2)[i];
  avgh[i] = packb((a.x + b.x + c.x) * (1.f / 3.f), (a.y + b.y + c.y) * (1.f / 3.f));
}

// ---------------------------------------------------------------------------
// MFMA transformer, row-ownership version (byte-identical to R12..R17).
// ---------------------------------------------------------------------------
__global__ __launch_bounds__(256, 3)
void seq_transformer(const int* __restrict__ seq, const int* __restrict__ lengths,
                     const float* __restrict__ bert, const short* __restrict__ avgh,
                     const float* __restrict__ pbias, const float* __restrict__ pos,
                     const short* __restrict__ pwB, const short* __restrict__ wqB,
                     const short* __restrict__ wkB, const short* __restrict__ wvB,
                     const short* __restrict__ woB, const short* __restrict__ w1B,
                     const short* __restrict__ w2B,
                     const float* __restrict__ b1, const float* __restrict__ b2,
                     const float* __restrict__ ln1g, const float* __restrict__ ln1b,
                     const float* __restrict__ ln2g, const float* __restrict__ ln2b,
                     const float* __restrict__ lnfg, const float* __restrict__ lnfb,
                     float* __restrict__ out) {
  __shared__ short xh[64 * PH];
  __shared__ short qh[64 * PH];
  __shared__ short kh[64 * PH];
  __shared__ short vt[64 * PH];
  __shared__ short s0[64 * PH];
  __shared__ int   sidx[64];

  const int t = threadIdx.x;
  const int lane = t & 63;
  const int mt = t >> 6;
  const int quad = lane >> 4;
  const int c0 = lane & 15;
  const int b = blockIdx.x;
  const int arow = mt * 16 + c0;

  if (t < 64) sidx[t] = (t < SS) ? seq[b * SS + t] : 0;
  __syncthreads();

  const int len = lengths[b];
  const float alpha = (len <= 10) ? 0.3f : ((len >= 50) ? 0.7f : 0.5f);
  const float isq = 0.17677669529663687f;

  float kbias[4];
#pragma unroll
  for (int nt = 0; nt < 4; ++nt) {
    int key = nt * 16 + c0;
    kbias[nt] = (key < SS && sidx[key] != 0) ? 0.f : -1e9f;
  }

#pragma unroll
  for (int ir = 0; ir < 16; ++ir) {
    int s = mt * 16 + ir;
    short v = 0;
    if (s < SS) v = avgh[(size_t)sidx[s] * SD + lane];
    qh[s * PH + lane] = v;
  }

  {
    f32x4 o4[4];
    mm64(qh, pwB, arow, quad, lane, o4);
#pragma unroll
    for (int nt = 0; nt < 4; ++nt) {
      int c = nt * 16 + c0;
      float pbv = pbias[c];
#pragma unroll
      for (int r = 0; r < 4; ++r) {
        int row = mt * 16 + quad * 4 + r;
        short ov = 0;
        if (row < SS) {
          float g = o4[nt][r] + pbv;
          float xv = alpha * bert[(size_t)sidx[row] * SD + c] +
                     (1.f - alpha) * g + pos[row * SD + c];
          ov = f2b(xv);
        }
        xh[row * PH + c] = ov;
      }
    }
  }

#pragma unroll 1
  for (int blk = 0; blk < NBLK; ++blk) {
    const short* Wq = wqB + blk * 4096;
    const short* Wk = wkB + blk * 4096;
    const short* Wv = wvB + blk * 4096;
    const short* Wo = woB + blk * 4096;
    const short* W1 = w1B + blk * 16384;
    const short* W2 = w2B + blk * 16384;

    __syncthreads();

    {
      f32x4 o4[4];
      mm64(xh, Wq, arow, quad, lane, o4);
#pragma unroll
      for (int nt = 0; nt < 4; ++nt) {
        int c = nt * 16 + c0;
#pragma unroll
        for (int r = 0; r < 4; ++r) qh[(mt * 16 + quad * 4 + r) * PH + c] = f2b(o4[nt][r]);
      }
      mm64(xh, Wk, arow, quad, lane, o4);
#pragma unroll
      for (int nt = 0; nt < 4; ++nt) {
        int c = nt * 16 + c0;
#pragma unroll
        for (int r = 0; r < 4; ++r) kh[(mt * 16 + quad * 4 + r) * PH + c] = f2b(o4[nt][r]);
      }
      mm64(xh, Wv, arow, quad, lane, o4);
#pragma unroll
      for (int nt = 0; nt < 4; ++nt) {
        int dim = nt * 16 + c0;
        unsigned p0 = packb(o4[nt][0], o4[nt][1]);
        unsigned p1 = packb(o4[nt][2], o4[nt][3]);
        *(uint2*)(vt + (size_t)dim * PH + mt * 16 + quad * 4) = make_uint2(p0, p1);
      }
    }
    __syncthreads();

#pragma unroll
    for (int h = 0; h < 2; ++h) {
      {
        bf16x8 aq = *(const bf16x8*)(qh + arow * PH + h * 32 + quad * 8);
        float p[4][4];
        float mx[4], sm[4];
#pragma unroll
        for (int nt = 0; nt < 4; ++nt) {
          int key = nt * 16 + c0;
          bf16x8 bk = *(const bf16x8*)(kh + key * PH + h * 32 + quad * 8);
          f32x4 acc = {0.f, 0.f, 0.f, 0.f};
          acc = __builtin_amdgcn_mfma_f32_16x16x32_bf16(aq, bk, acc, 0, 0, 0);
#pragma unroll
          for (int r = 0; r < 4; ++r) p[nt][r] = fmaf(acc[r], isq, kbias[nt]);
        }
#pragma unroll
        for (int r = 0; r < 4; ++r)
          mx[r] = fmaxf(fmaxf(p[0][r], p[1][r]), fmaxf(p[2][r], p[3][r]));
#pragma unroll
        for (int o = 1; o < 16; o <<= 1)
#pragma unroll
          for (int r = 0; r < 4; ++r) mx[r] = fmaxf(mx[r], __shfl_xor(mx[r], o, 64));
#pragma unroll
        for (int r = 0; r < 4; ++r) sm[r] = 0.f;
#pragma unroll
        for (int nt = 0; nt < 4; ++nt)
#pragma unroll
          for (int r = 0; r < 4; ++r) {
            float e = __expf(p[nt][r] - mx[r]);
            p[nt][r] = e;
            sm[r] += e;
          }
#pragma unroll
        for (int o = 1; o < 16; o <<= 1)
#pragma unroll
          for (int r = 0; r < 4; ++r) sm[r] += __shfl_xor(sm[r], o, 64);
#pragma unroll
        for (int r = 0; r < 4; ++r) {
          float inv = __builtin_amdgcn_rcpf(sm[r]);
          int q = mt * 16 + quad * 4 + r;
#pragma unroll
          for (int nt = 0; nt < 4; ++nt)
            s0[q * PH + nt * 16 + c0] = f2b(p[nt][r] * inv);
        }
      }
      {
        bf16x8 a0 = *(const bf16x8*)(s0 + arow * PH + quad * 8);
        bf16x8 a1 = *(const bf16x8*)(s0 + arow * PH + 32 + quad * 8);
#pragma unroll
        for (int nt = 0; nt < 2; ++nt) {
          int dim = h * 32 + nt * 16 + c0;
          bf16x8 b0 = *(const bf16x8*)(vt + (size_t)dim * PH + quad * 8);
          bf16x8 b1v = *(const bf16x8*)(vt + (size_t)dim * PH + 32 + quad * 8);
          f32x4 acc = {0.f, 0.f, 0.f, 0.f};
          acc = __builtin_amdgcn_mfma_f32_16x16x32_bf16(a0, b0, acc, 0, 0, 0);
          acc = __builtin_amdgcn_mfma_f32_16x16x32_bf16(a1, b1v, acc, 0, 0, 0);
#pragma unroll
          for (int r = 0; r < 4; ++r)
            qh[(mt * 16 + quad * 4 + r) * PH + dim] = f2b(acc[r]);
        }
      }
    }

    {
      f32x4 o4[4];
      mm64(qh, Wo, arow, quad, lane, o4);
      ln_epilogue(o4, xh, ln1g + blk * SD, ln1b + blk * SD, nullptr, mt, quad, c0);
    }

    f32x4 facc[4];
#pragma unroll
    for (int nt = 0; nt < 4; ++nt) facc[nt] = (f32x4){0.f, 0.f, 0.f, 0.f};
#pragma unroll 1
    for (int c = 0; c < 4; ++c) {
      {
        bf16x8 a0 = *(const bf16x8*)(xh + arow * PH + quad * 8);
        bf16x8 a1 = *(const bf16x8*)(xh + arow * PH + 32 + quad * 8);
#pragma unroll
        for (int nt = 0; nt < 4; ++nt) {
          int ntg = c * 4 + nt;
          f32x4 acc = {0.f, 0.f, 0.f, 0.f};
          acc = __builtin_amdgcn_mfma_f32_16x16x32_bf16(a0, ldB(W1, 0 * 16 + ntg, lane), acc, 0, 0, 0);
          acc = __builtin_amdgcn_mfma_f32_16x16x32_bf16(a1, ldB(W1, 1 * 16 + ntg, lane), acc, 0, 0, 0);
          int cc = nt * 16 + c0;
          float b1v = b1[blk * 256 + c * 64 + cc];
#pragma unroll
          for (int r = 0; r < 4; ++r)
            qh[(mt * 16 + quad * 4 + r) * PH + cc] = f2b(gelu_fast(acc[r] + b1v));
        }
      }
      {
        bf16x8 a0 = *(const bf16x8*)(qh + arow * PH + quad * 8);
        bf16x8 a1 = *(const bf16x8*)(qh + arow * PH + 32 + quad * 8);
#pragma unroll
        for (int nt = 0; nt < 4; ++nt) {
          facc[nt] = __builtin_amdgcn_mfma_f32_16x16x32_bf16(a0, ldB(W2, (2 * c) * 4 + nt, lane), facc[nt], 0, 0, 0);
          facc[nt] = __builtin_amdgcn_mfma_f32_16x16x32_bf16(a1, ldB(W2, (2 * c + 1) * 4 + nt, lane), facc[nt], 0, 0, 0);
        }
      }
    }

    ln_epilogue(facc, xh, ln2g + blk * SD, ln2b + blk * SD, b2 + blk * SD, mt, quad, c0);
  }
  __syncthreads();

  if (mt == 0) {
    int sl = len - 1;
    float val = b2f(xh[sl * PH + lane]);
    float2 ss = wred_sum2(val, val * val);
    float m = ss.x * (1.f / 64);
    float var = fmaxf(ss.y * (1.f / 64) - m * m, 0.f);
    float rs = rsqrtf(var + 1e-5f);
    out[b * SD + lane] = (val - m) * rs * lnfg[lane] + lnfb[lane];
  }
}

// ---------------------------------------------------------------------------
extern "C" void kernel_launch(void* const* d_in, const int* in_sizes, int n_in,
                              void* d_out, int out_size, void* d_ws, size_t ws_size,
                              hipStream_t stream) {
  const int*   seq   = (const int*)d_in[0];
  const int*   lens  = (const int*)d_in[1];
  const int*   ei    = (const int*)d_in[2];
  const float* ew    = (const float*)d_in[3];
  const float* bert  = (const float*)d_in[4];
  const float* gnn   = (const float*)d_in[5];
  const float* pw    = (const float*)d_in[6];
  const float* pb    = (const float*)d_in[7];
  const float* pos   = (const float*)d_in[8];
  const float* wq    = (const float*)d_in[9];
  const float* wk    = (const float*)d_in[10];
  const float* wv    = (const float*)d_in[11];
  const float* wo    = (const float*)d_in[12];
  const float* w1    = (const float*)d_in[13];
  const float* b1    = (const float*)d_in[14];
  const float* w2    = (const float*)d_in[15];
  const float* b2    = (const float*)d_in[16];
  const float* ln1g  = (const float*)d_in[17];
  const float* ln1b  = (const float*)d_in[18];
  const float* ln2g  = (const float*)d_in[19];
  const float* ln2b  = (const float*)d_in[20];
  const float* lnfg  = (const float*)d_in[21];
  const float* lnfb  = (const float*)d_in[22];
  float* out = (float*)d_out;

  const int E = in_sizes[2] / 2;          // 1,000,000
  const int B = in_sizes[0] / SS;         // 1024
  const int N = in_sizes[4] / SD;         // 100,001
  const int BS = B * SS;                  // 51,200

  const int* esrc = ei;
  const int* edst = ei + E;

  const int Nr = (N + 1023) & ~1023;      // rounded for zero loops
  const int NF = (N + 15) & ~15;          // flag bytes, padded
  const int n32 = N * 32;

  // ---- workspace layout; (cs, cap) degraded until it fits
  short* pwB; short* wqB; short* wkB; short* wvB; short* woB; short* w1B; short* w2B;
  unsigned* gnnh; unsigned* g1xh; unsigned* avgh;
  int* cntp; unsigned char* flags; int* ovcnt; int4* ov; int2* ep;
  int cs = 4, cap = 32;
  auto layout = [&](int cstride, int capv) -> size_t {
    pwB = (short*)d_ws;
    wqB = pwB + 4096;
    wkB = wqB + 8192;
    wvB = wkB + 8192;
    woB = wvB + 8192;
    w1B = woB + 8192;
    w2B = w1B + 32768;
    gnnh = (unsigned*)(w2B + 32768);
    g1xh = gnnh + (size_t)N * 32;
    cntp = (int*)(g1xh + (size_t)N * 32);
    flags = (unsigned char*)(cntp + (size_t)Nr * cstride);
    ovcnt = (int*)(flags + NF);
    ov = (int4*)(ovcnt + 4);
    ep = (int2*)(ov + OVCAP);
    avgh = gnnh;   // avgh ALIASES gnnh (dead after gather1)
    return (size_t)((char*)(ep + (size_t)N * capv) - (char*)d_ws);
  };
  size_t need = layout(4, 32); cs = 4; cap = 32;
  if (need > ws_size) { need = layout(1, 32); cs = 1; cap = 32; }
  if (need > ws_size) { need = layout(1, 24); cs = 1; cap = 24; }

  // fp32 fallback tables (overlay everything after g1xh)
  float* g1x = (float*)cntp;
  float* g2x = g1x + (size_t)N * SD;
  size_t need_fb = (size_t)((char*)(g2x + (size_t)N * SD) - (char*)d_ws);

  if (need <= ws_size) {
    const int cntn = Nr * cs;
    prep_zero<<<1024, 256, 0, stream>>>(pw, wq, wk, wv, wo, w1, w2,
                                        pwB, wqB, wkB, wvB, woB, w1B, w2B,
                                        gnn, gnnh, n32, cntp, cntn,
                                        (int*)flags, NF / 4, ovcnt);
    gnn_build<<<1024, 256, 0, stream>>>(esrc, edst, ew, cntp, cs, cap, ep,
                                        ov, ovcnt, seq, flags, BS, E, N);
    const int nb = (N + 3) / 4;
    gnn_gather1<<<nb, 256, 0, stream>>>(gnnh, cntp, cs, cap, ep, ov, ovcnt,
                                        g1xh, N);
    gnn_gather_avg<<<nb, 256, 0, stream>>>(g1xh, cntp, cs, cap, ep, ov, ovcnt,
                                           gnn, avgh, N, flags);
  } else if (ws_size >= need_fb) {
    prep_zero<<<1024, 256, 0, stream>>>(pw, wq, wk, wv, wo, w1, w2,
                                        pwB, wqB, wkB, wvB, woB, w1B, w2B,
                                        gnn, gnnh, n32, (int*)d_ws, 0,
                                        (int*)d_ws, 0, (int*)d_ws);
    hipMemsetAsync(g1x, 0, (size_t)2 * N * SD * sizeof(float), stream);
    const long total = (long)E * 64;
    const int sblocks = (int)((total + 255) / 256);
    gnn_scatter<<<sblocks, 256, 0, stream>>>(gnn, esrc, edst, ew, g1x, E);
    gnn_scatter<<<sblocks, 256, 0, stream>>>(g1x, esrc, edst, ew, g2x, E);
    avg_from_f32<<<(n32 + 255) / 256, 256, 0, stream>>>(gnn, g1x, g2x, avgh, n32);
  }

  seq_transformer<<<B, 256, 0, stream>>>(
      seq, lens, bert, (const short*)avgh, pb, pos,
      pwB, wqB, wkB, wvB, woB, w1B, w2B,
      b1, b2, ln1g, ln1b, ln2g, ln2b, lnfg, lnfb, out);
}